// Round 1
// baseline (1886.358 us; speedup 1.0000x reference)
//
#include <hip/hip_runtime.h>

static __device__ __forceinline__ void fma4(float4& a, float s, const float4& w){
  a.x = fmaf(s, w.x, a.x); a.y = fmaf(s, w.y, a.y);
  a.z = fmaf(s, w.z, a.z); a.w = fmaf(s, w.w, a.w);
}

// ---------------- mean of edge weights ----------------
__global__ void mean_kernel(const float* __restrict__ ew, float* __restrict__ msum, int E){
  float s = 0.f;
  for (int i = blockIdx.x*blockDim.x + threadIdx.x; i < E; i += gridDim.x*blockDim.x) s += ew[i];
  for (int d = 32; d > 0; d >>= 1) s += __shfl_down(s, d, 64);
  __shared__ float ps[4];
  int lane = threadIdx.x & 63, w = threadIdx.x >> 6;
  if (lane == 0) ps[w] = s;
  __syncthreads();
  if (threadIdx.x == 0){
    float tot = ps[0] + ps[1] + ps[2] + ps[3];
    atomicAdd(msum, tot / (float)E);
  }
}

// ---------------- fused: h0 = x@Wpre ; xl = h0@Wl+bl ; xr = h0@Wr+br ----------------
__global__ __launch_bounds__(256) void fused_pre(
    const float* __restrict__ x,
    const float* __restrict__ Wpre,
    const float* __restrict__ Wl, const float* __restrict__ bl,
    const float* __restrict__ Wr, const float* __restrict__ br,
    float* __restrict__ h0out, float* __restrict__ xlout, float* __restrict__ xrout,
    int N)
{
  __shared__ float xs[64*32];     // A chunk  [64 rows][32 k]
  __shared__ float wsd[32*128];   // W chunk  [32 k][128 cols]
  __shared__ float h0s[64*128];   // h0 tile
  const int t = threadIdx.x;
  const int row0 = blockIdx.x * 64;
  const int cgrp = t & 31, rgrp = t >> 5;
  const int c0 = cgrp * 4, r0 = rgrp * 8;

  float4 acc[8];
  #pragma unroll
  for (int i = 0; i < 8; ++i) acc[i] = make_float4(0.f,0.f,0.f,0.f);

  // ---- stage 1: h0 tile ----
  for (int k0 = 0; k0 < 128; k0 += 32){
    #pragma unroll
    for (int j = 0; j < 2; ++j){
      int idx = t + j*256;
      int r = idx >> 3, k4 = idx & 7;
      int grow = row0 + r;
      float4 v = make_float4(0.f,0.f,0.f,0.f);
      if (grow < N) v = *(const float4*)&x[(size_t)grow*128 + k0 + k4*4];
      *(float4*)&xs[r*32 + k4*4] = v;
    }
    #pragma unroll
    for (int j = 0; j < 4; ++j){
      int idx = t + j*256;
      int kr = idx >> 5, c4 = idx & 31;
      *(float4*)&wsd[kr*128 + c4*4] = *(const float4*)&Wpre[(size_t)(k0+kr)*128 + c4*4];
    }
    __syncthreads();
    #pragma unroll
    for (int k4 = 0; k4 < 8; ++k4){
      float4 wv0 = *(const float4*)&wsd[(k4*4+0)*128 + c0];
      float4 wv1 = *(const float4*)&wsd[(k4*4+1)*128 + c0];
      float4 wv2 = *(const float4*)&wsd[(k4*4+2)*128 + c0];
      float4 wv3 = *(const float4*)&wsd[(k4*4+3)*128 + c0];
      #pragma unroll
      for (int i = 0; i < 8; ++i){
        float4 xv = *(const float4*)&xs[(r0+i)*32 + k4*4];
        fma4(acc[i], xv.x, wv0); fma4(acc[i], xv.y, wv1);
        fma4(acc[i], xv.z, wv2); fma4(acc[i], xv.w, wv3);
      }
    }
    __syncthreads();
  }
  #pragma unroll
  for (int i = 0; i < 8; ++i){
    int grow = row0 + r0 + i;
    *(float4*)&h0s[(r0+i)*128 + c0] = acc[i];
    if (grow < N) *(float4*)&h0out[(size_t)grow*128 + c0] = acc[i];
  }
  __syncthreads();

  // ---- stage 2/3: xl = h0@Wl+bl, xr = h0@Wr+br ----
  for (int pass = 0; pass < 2; ++pass){
    const float* Wp  = pass ? Wr : Wl;
    const float* bp  = pass ? br : bl;
    float* outp      = pass ? xrout : xlout;
    #pragma unroll
    for (int i = 0; i < 8; ++i) acc[i] = make_float4(0.f,0.f,0.f,0.f);
    for (int k0 = 0; k0 < 128; k0 += 32){
      #pragma unroll
      for (int j = 0; j < 4; ++j){
        int idx = t + j*256;
        int kr = idx >> 5, c4 = idx & 31;
        *(float4*)&wsd[kr*128 + c4*4] = *(const float4*)&Wp[(size_t)(k0+kr)*128 + c4*4];
      }
      __syncthreads();
      #pragma unroll
      for (int k4 = 0; k4 < 8; ++k4){
        int kg = k0 + k4*4;
        float4 wv0 = *(const float4*)&wsd[(k4*4+0)*128 + c0];
        float4 wv1 = *(const float4*)&wsd[(k4*4+1)*128 + c0];
        float4 wv2 = *(const float4*)&wsd[(k4*4+2)*128 + c0];
        float4 wv3 = *(const float4*)&wsd[(k4*4+3)*128 + c0];
        #pragma unroll
        for (int i = 0; i < 8; ++i){
          float4 xv = *(const float4*)&h0s[(r0+i)*128 + kg];
          fma4(acc[i], xv.x, wv0); fma4(acc[i], xv.y, wv1);
          fma4(acc[i], xv.z, wv2); fma4(acc[i], xv.w, wv3);
        }
      }
      __syncthreads();
    }
    float4 bv = *(const float4*)&bp[c0];
    #pragma unroll
    for (int i = 0; i < 8; ++i){
      int grow = row0 + r0 + i;
      if (grow < N){
        float4 v = acc[i];
        v.x += bv.x; v.y += bv.y; v.z += bv.z; v.w += bv.w;
        *(float4*)&outp[(size_t)grow*128 + c0] = v;
      }
    }
  }
}

// ---------------- generic 128x128 GEMM: out = act(A@W + bias) ----------------
__global__ __launch_bounds__(256) void gemm128_kernel(
    const float* __restrict__ A, const float* __restrict__ W,
    const float* __restrict__ bias, float* __restrict__ out, int N, int relu)
{
  __shared__ float xs[64*32];
  __shared__ float wsd[32*128];
  const int t = threadIdx.x;
  const int row0 = blockIdx.x * 64;
  const int cgrp = t & 31, rgrp = t >> 5;
  const int c0 = cgrp * 4, r0 = rgrp * 8;

  float4 acc[8];
  #pragma unroll
  for (int i = 0; i < 8; ++i) acc[i] = make_float4(0.f,0.f,0.f,0.f);

  for (int k0 = 0; k0 < 128; k0 += 32){
    #pragma unroll
    for (int j = 0; j < 2; ++j){
      int idx = t + j*256;
      int r = idx >> 3, k4 = idx & 7;
      int grow = row0 + r;
      float4 v = make_float4(0.f,0.f,0.f,0.f);
      if (grow < N) v = *(const float4*)&A[(size_t)grow*128 + k0 + k4*4];
      *(float4*)&xs[r*32 + k4*4] = v;
    }
    #pragma unroll
    for (int j = 0; j < 4; ++j){
      int idx = t + j*256;
      int kr = idx >> 5, c4 = idx & 31;
      *(float4*)&wsd[kr*128 + c4*4] = *(const float4*)&W[(size_t)(k0+kr)*128 + c4*4];
    }
    __syncthreads();
    #pragma unroll
    for (int k4 = 0; k4 < 8; ++k4){
      float4 wv0 = *(const float4*)&wsd[(k4*4+0)*128 + c0];
      float4 wv1 = *(const float4*)&wsd[(k4*4+1)*128 + c0];
      float4 wv2 = *(const float4*)&wsd[(k4*4+2)*128 + c0];
      float4 wv3 = *(const float4*)&wsd[(k4*4+3)*128 + c0];
      #pragma unroll
      for (int i = 0; i < 8; ++i){
        float4 xv = *(const float4*)&xs[(r0+i)*32 + k4*4];
        fma4(acc[i], xv.x, wv0); fma4(acc[i], xv.y, wv1);
        fma4(acc[i], xv.z, wv2); fma4(acc[i], xv.w, wv3);
      }
    }
    __syncthreads();
  }
  float4 bv = *(const float4*)&bias[c0];
  #pragma unroll
  for (int i = 0; i < 8; ++i){
    int grow = row0 + r0 + i;
    if (grow < N){
      float4 v = acc[i];
      v.x += bv.x; v.y += bv.y; v.z += bv.z; v.w += bv.w;
      if (relu){
        v.x = fmaxf(v.x, 0.f); v.y = fmaxf(v.y, 0.f);
        v.z = fmaxf(v.z, 0.f); v.w = fmaxf(v.w, 0.f);
      }
      *(float4*)&out[(size_t)grow*128 + c0] = v;
    }
  }
}

// ---------------- classifier: logits = A@W2 + b2  (128 -> 40) ----------------
__global__ __launch_bounds__(320) void cls_kernel(
    const float* __restrict__ A, const float* __restrict__ W2,
    const float* __restrict__ b2, float* __restrict__ out, int N)
{
  __shared__ float ts[64*128];   // 32KB
  __shared__ float w2s[128*40];  // 20KB  natural layout [k][c]
  const int t = threadIdx.x;
  const int row0 = blockIdx.x * 64;
  for (int idx = t; idx < 128*40; idx += 320) w2s[idx] = W2[idx];
  for (int idx = t; idx < 2048; idx += 320){
    int r = idx >> 5, c4 = idx & 31;
    int grow = row0 + r;
    float4 v = make_float4(0.f,0.f,0.f,0.f);
    if (grow < N) v = *(const float4*)&A[(size_t)grow*128 + c4*4];
    *(float4*)&ts[r*128 + c4*4] = v;
  }
  __syncthreads();
  const int c  = t % 40;
  const int rg = t / 40;        // 0..7
  const int r0 = rg * 8;
  float acc[8];
  #pragma unroll
  for (int i = 0; i < 8; ++i) acc[i] = 0.f;
  for (int k4 = 0; k4 < 32; ++k4){
    float w0 = w2s[(k4*4+0)*40 + c];
    float w1 = w2s[(k4*4+1)*40 + c];
    float w2_ = w2s[(k4*4+2)*40 + c];
    float w3 = w2s[(k4*4+3)*40 + c];
    #pragma unroll
    for (int i = 0; i < 8; ++i){
      float4 xv = *(const float4*)&ts[(r0+i)*128 + k4*4];
      acc[i] += xv.x*w0 + xv.y*w1 + xv.z*w2_ + xv.w*w3;
    }
  }
  float bv = b2[c];
  #pragma unroll
  for (int i = 0; i < 8; ++i){
    int grow = row0 + r0 + i;
    if (grow < N) out[(size_t)grow*40 + c] = acc[i] + bv;
  }
}

// ---------------- edge pass: alpha -> exp -> atomic numer/denom ----------------
__global__ __launch_bounds__(256) void edge_kernel(
    const int* __restrict__ ei, const float* __restrict__ ew,
    const float* __restrict__ xl, const float* __restrict__ xr,
    const float* __restrict__ We, const float* __restrict__ att,
    const float* __restrict__ msum,
    float* __restrict__ numer, float* __restrict__ denom,
    int E, int N)
{
  const int wid  = threadIdx.x >> 6;
  const int lane = threadIdx.x & 63;
  const int e = blockIdx.x * 4 + wid;
  const int Etot = E + N;
  if (e >= Etot) return;
  int src, dst; float w;
  if (e < E){ src = ei[e]; dst = ei[E + e]; w = ew[e]; }
  else      { src = dst = e - E; w = msum[0]; }

  float2 xlv = *(const float2*)&xl[(size_t)src*128 + lane*2];
  float2 xrv = *(const float2*)&xr[(size_t)dst*128 + lane*2];
  float2 wev = *(const float2*)&We[lane*2];
  float e0 = xlv.x + xrv.x + w*wev.x;
  float e1 = xlv.y + xrv.y + w*wev.y;
  e0 = e0 > 0.f ? e0 : 0.2f*e0;
  e1 = e1 > 0.f ? e1 : 0.2f*e1;

  const int hd = lane >> 4, m = lane & 15;
  float a0 = att[hd*32 + 2*m];
  float a1 = att[hd*32 + 2*m + 1];
  float s = e0*a0 + e1*a1;
  s += __shfl_xor(s, 1, 64);
  s += __shfl_xor(s, 2, 64);
  s += __shfl_xor(s, 4, 64);
  s += __shfl_xor(s, 8, 64);     // alpha for this head (no max-shift: softmax is shift-invariant)
  float ex = expf(s);

  if (m == 0) atomicAdd(&denom[(size_t)dst*4 + hd], ex);
  atomicAdd(&numer[(size_t)dst*128 + 2*lane    ], ex*xlv.x);
  atomicAdd(&numer[(size_t)dst*128 + 2*lane + 1], ex*xlv.y);
}

// ---------------- per-node epilogue: h = h0 + elu(numer/denom + b_gat) ----------------
__global__ void epilogue_kernel(
    const float* __restrict__ numer, const float* __restrict__ denom,
    const float* __restrict__ bgat, float* __restrict__ hbuf, int N)
{
  int idx = blockIdx.x*blockDim.x + threadIdx.x;
  if (idx >= N*128) return;
  int n = idx >> 7, ch = idx & 127, hd = ch >> 5;
  float d = denom[n*4 + hd] + 1e-16f;
  float o = numer[idx] / d + bgat[ch];
  float h1 = o > 0.f ? o : expm1f(o);
  hbuf[idx] += h1;
}

extern "C" void kernel_launch(void* const* d_in, const int* in_sizes, int n_in,
                              void* d_out, int out_size, void* d_ws, size_t ws_size,
                              hipStream_t stream)
{
  const float* x    = (const float*)d_in[0];
  const int*   ei   = (const int*)  d_in[1];
  const float* ew   = (const float*)d_in[2];
  const float* Wpre = (const float*)d_in[3];
  const float* Wl   = (const float*)d_in[4];
  const float* bl   = (const float*)d_in[5];
  const float* Wr   = (const float*)d_in[6];
  const float* br   = (const float*)d_in[7];
  const float* We   = (const float*)d_in[8];
  const float* att  = (const float*)d_in[9];
  const float* bgat = (const float*)d_in[10];
  const float* W1   = (const float*)d_in[11];
  const float* b1   = (const float*)d_in[12];
  const float* W2   = (const float*)d_in[13];
  const float* b2   = (const float*)d_in[14];

  const int N = in_sizes[0] / 128;
  const int E = in_sizes[2];

  float* hout   = (float*)d_out;              // [N,128]
  float* logits = hout + (size_t)N*128;       // [N,40]

  float* xl    = (float*)d_ws;                // [N,128]
  float* xr    = xl    + (size_t)N*128;       // [N,128]
  float* numer = xr    + (size_t)N*128;       // [N,128]
  float* denom = numer + (size_t)N*128;       // [N,4]
  float* msum  = denom + (size_t)N*4;         // [1]
  float* tbuf  = xl;                          // reuse after edge phase

  // zero numer + denom + msum (contiguous)
  hipMemsetAsync(numer, 0, ((size_t)N*132 + 1)*sizeof(float), stream);

  mean_kernel<<<256, 256, 0, stream>>>(ew, msum, E);
  fused_pre<<<(N+63)/64, 256, 0, stream>>>(x, Wpre, Wl, bl, Wr, br, hout, xl, xr, N);

  const int Etot = E + N;
  edge_kernel<<<(Etot+3)/4, 256, 0, stream>>>(ei, ew, xl, xr, We, att, msum, numer, denom, E, N);
  epilogue_kernel<<<((N*128)+255)/256, 256, 0, stream>>>(numer, denom, bgat, hout, N);

  gemm128_kernel<<<(N+63)/64, 256, 0, stream>>>(hout, W1, b1, tbuf, N, 1);
  cls_kernel<<<(N+63)/64, 320, 0, stream>>>(tbuf, W2, b2, logits, N);
}

// Round 2
// 795.229 us; speedup vs baseline: 2.3721x; 2.3721x over previous
//
#include <hip/hip_runtime.h>

static __device__ __forceinline__ void fma4(float4& a, float s, const float4& w){
  a.x = fmaf(s, w.x, a.x); a.y = fmaf(s, w.y, a.y);
  a.z = fmaf(s, w.z, a.z); a.w = fmaf(s, w.w, a.w);
}

// ---------------- mean of edge weights ----------------
__global__ void mean_kernel(const float* __restrict__ ew, float* __restrict__ msum, int E){
  float s = 0.f;
  for (int i = blockIdx.x*blockDim.x + threadIdx.x; i < E; i += gridDim.x*blockDim.x) s += ew[i];
  for (int d = 32; d > 0; d >>= 1) s += __shfl_down(s, d, 64);
  __shared__ float ps[4];
  int lane = threadIdx.x & 63, w = threadIdx.x >> 6;
  if (lane == 0) ps[w] = s;
  __syncthreads();
  if (threadIdx.x == 0){
    float tot = ps[0] + ps[1] + ps[2] + ps[3];
    atomicAdd(msum, tot / (float)E);
  }
}

// ---------------- CSR build: histogram ----------------
__global__ void count_kernel(const int* __restrict__ ei, int* __restrict__ deg, int E){
  int e = blockIdx.x*256 + threadIdx.x;
  if (e < E) atomicAdd(&deg[ei[E + e]], 1);
}

// block-level inclusive scan (256) -> rowptr partial + block sums
__global__ __launch_bounds__(256) void scan1_kernel(const int* __restrict__ deg, int* __restrict__ rowptr,
                                                    int* __restrict__ bsum, int N){
  __shared__ int s[256];
  int i = blockIdx.x*256 + threadIdx.x;
  int v = (i < N) ? deg[i] : 0;
  s[threadIdx.x] = v;
  __syncthreads();
  for (int off = 1; off < 256; off <<= 1){
    int t = (threadIdx.x >= off) ? s[threadIdx.x - off] : 0;
    __syncthreads();
    s[threadIdx.x] += t;
    __syncthreads();
  }
  if (i < N) rowptr[i + 1] = s[threadIdx.x];
  if (threadIdx.x == 255) bsum[blockIdx.x] = s[255];
}

// single-block scan of block sums (nb <= 512) -> exclusive offsets
__global__ __launch_bounds__(512) void scan2_kernel(const int* __restrict__ bsum, int* __restrict__ boff, int nb){
  __shared__ int s[512];
  int v = (threadIdx.x < nb) ? bsum[threadIdx.x] : 0;
  s[threadIdx.x] = v;
  __syncthreads();
  for (int off = 1; off < 512; off <<= 1){
    int t = (threadIdx.x >= off) ? s[threadIdx.x - off] : 0;
    __syncthreads();
    s[threadIdx.x] += t;
    __syncthreads();
  }
  if (threadIdx.x < nb) boff[threadIdx.x] = s[threadIdx.x] - v;
}

__global__ void scan3_kernel(int* __restrict__ rowptr, const int* __restrict__ boff, int N){
  int i = blockIdx.x*256 + threadIdx.x;
  if (i == 0) rowptr[0] = 0;
  if (i < N) rowptr[i + 1] += boff[i >> 8];
}

// scatter edges into dst-sorted order
__global__ void fill_kernel(const int* __restrict__ ei, const float* __restrict__ ew,
                            int* __restrict__ cursor, int* __restrict__ ssrc,
                            float* __restrict__ sw, int E){
  int e = blockIdx.x*256 + threadIdx.x;
  if (e >= E) return;
  int dst = ei[E + e];
  int pos = atomicAdd(&cursor[dst], 1);
  ssrc[pos] = ei[e];
  sw[pos]   = ew[e];
}

// ---------------- fused: h0 = x@Wpre ; xl = h0@Wl+bl ; xr = h0@Wr+br ----------------
__global__ __launch_bounds__(256) void fused_pre(
    const float* __restrict__ x,
    const float* __restrict__ Wpre,
    const float* __restrict__ Wl, const float* __restrict__ bl,
    const float* __restrict__ Wr, const float* __restrict__ br,
    float* __restrict__ h0out, float* __restrict__ xlout, float* __restrict__ xrout,
    int N)
{
  __shared__ float xs[64*32];     // A chunk  [64 rows][32 k]
  __shared__ float wsd[32*128];   // W chunk  [32 k][128 cols]
  __shared__ float h0s[64*128];   // h0 tile
  const int t = threadIdx.x;
  const int row0 = blockIdx.x * 64;
  const int cgrp = t & 31, rgrp = t >> 5;
  const int c0 = cgrp * 4, r0 = rgrp * 8;

  float4 acc[8];
  #pragma unroll
  for (int i = 0; i < 8; ++i) acc[i] = make_float4(0.f,0.f,0.f,0.f);

  for (int k0 = 0; k0 < 128; k0 += 32){
    #pragma unroll
    for (int j = 0; j < 2; ++j){
      int idx = t + j*256;
      int r = idx >> 3, k4 = idx & 7;
      int grow = row0 + r;
      float4 v = make_float4(0.f,0.f,0.f,0.f);
      if (grow < N) v = *(const float4*)&x[(size_t)grow*128 + k0 + k4*4];
      *(float4*)&xs[r*32 + k4*4] = v;
    }
    #pragma unroll
    for (int j = 0; j < 4; ++j){
      int idx = t + j*256;
      int kr = idx >> 5, c4 = idx & 31;
      *(float4*)&wsd[kr*128 + c4*4] = *(const float4*)&Wpre[(size_t)(k0+kr)*128 + c4*4];
    }
    __syncthreads();
    #pragma unroll
    for (int k4 = 0; k4 < 8; ++k4){
      float4 wv0 = *(const float4*)&wsd[(k4*4+0)*128 + c0];
      float4 wv1 = *(const float4*)&wsd[(k4*4+1)*128 + c0];
      float4 wv2 = *(const float4*)&wsd[(k4*4+2)*128 + c0];
      float4 wv3 = *(const float4*)&wsd[(k4*4+3)*128 + c0];
      #pragma unroll
      for (int i = 0; i < 8; ++i){
        float4 xv = *(const float4*)&xs[(r0+i)*32 + k4*4];
        fma4(acc[i], xv.x, wv0); fma4(acc[i], xv.y, wv1);
        fma4(acc[i], xv.z, wv2); fma4(acc[i], xv.w, wv3);
      }
    }
    __syncthreads();
  }
  #pragma unroll
  for (int i = 0; i < 8; ++i){
    int grow = row0 + r0 + i;
    *(float4*)&h0s[(r0+i)*128 + c0] = acc[i];
    if (grow < N) *(float4*)&h0out[(size_t)grow*128 + c0] = acc[i];
  }
  __syncthreads();

  for (int pass = 0; pass < 2; ++pass){
    const float* Wp  = pass ? Wr : Wl;
    const float* bp  = pass ? br : bl;
    float* outp      = pass ? xrout : xlout;
    #pragma unroll
    for (int i = 0; i < 8; ++i) acc[i] = make_float4(0.f,0.f,0.f,0.f);
    for (int k0 = 0; k0 < 128; k0 += 32){
      #pragma unroll
      for (int j = 0; j < 4; ++j){
        int idx = t + j*256;
        int kr = idx >> 5, c4 = idx & 31;
        *(float4*)&wsd[kr*128 + c4*4] = *(const float4*)&Wp[(size_t)(k0+kr)*128 + c4*4];
      }
      __syncthreads();
      #pragma unroll
      for (int k4 = 0; k4 < 8; ++k4){
        int kg = k0 + k4*4;
        float4 wv0 = *(const float4*)&wsd[(k4*4+0)*128 + c0];
        float4 wv1 = *(const float4*)&wsd[(k4*4+1)*128 + c0];
        float4 wv2 = *(const float4*)&wsd[(k4*4+2)*128 + c0];
        float4 wv3 = *(const float4*)&wsd[(k4*4+3)*128 + c0];
        #pragma unroll
        for (int i = 0; i < 8; ++i){
          float4 xv = *(const float4*)&h0s[(r0+i)*128 + kg];
          fma4(acc[i], xv.x, wv0); fma4(acc[i], xv.y, wv1);
          fma4(acc[i], xv.z, wv2); fma4(acc[i], xv.w, wv3);
        }
      }
      __syncthreads();
    }
    float4 bv = *(const float4*)&bp[c0];
    #pragma unroll
    for (int i = 0; i < 8; ++i){
      int grow = row0 + r0 + i;
      if (grow < N){
        float4 v = acc[i];
        v.x += bv.x; v.y += bv.y; v.z += bv.z; v.w += bv.w;
        *(float4*)&outp[(size_t)grow*128 + c0] = v;
      }
    }
  }
}

// ---------------- generic 128x128 GEMM: out = act(A@W + bias) ----------------
__global__ __launch_bounds__(256) void gemm128_kernel(
    const float* __restrict__ A, const float* __restrict__ W,
    const float* __restrict__ bias, float* __restrict__ out, int N, int relu)
{
  __shared__ float xs[64*32];
  __shared__ float wsd[32*128];
  const int t = threadIdx.x;
  const int row0 = blockIdx.x * 64;
  const int cgrp = t & 31, rgrp = t >> 5;
  const int c0 = cgrp * 4, r0 = rgrp * 8;

  float4 acc[8];
  #pragma unroll
  for (int i = 0; i < 8; ++i) acc[i] = make_float4(0.f,0.f,0.f,0.f);

  for (int k0 = 0; k0 < 128; k0 += 32){
    #pragma unroll
    for (int j = 0; j < 2; ++j){
      int idx = t + j*256;
      int r = idx >> 3, k4 = idx & 7;
      int grow = row0 + r;
      float4 v = make_float4(0.f,0.f,0.f,0.f);
      if (grow < N) v = *(const float4*)&A[(size_t)grow*128 + k0 + k4*4];
      *(float4*)&xs[r*32 + k4*4] = v;
    }
    #pragma unroll
    for (int j = 0; j < 4; ++j){
      int idx = t + j*256;
      int kr = idx >> 5, c4 = idx & 31;
      *(float4*)&wsd[kr*128 + c4*4] = *(const float4*)&W[(size_t)(k0+kr)*128 + c4*4];
    }
    __syncthreads();
    #pragma unroll
    for (int k4 = 0; k4 < 8; ++k4){
      float4 wv0 = *(const float4*)&wsd[(k4*4+0)*128 + c0];
      float4 wv1 = *(const float4*)&wsd[(k4*4+1)*128 + c0];
      float4 wv2 = *(const float4*)&wsd[(k4*4+2)*128 + c0];
      float4 wv3 = *(const float4*)&wsd[(k4*4+3)*128 + c0];
      #pragma unroll
      for (int i = 0; i < 8; ++i){
        float4 xv = *(const float4*)&xs[(r0+i)*32 + k4*4];
        fma4(acc[i], xv.x, wv0); fma4(acc[i], xv.y, wv1);
        fma4(acc[i], xv.z, wv2); fma4(acc[i], xv.w, wv3);
      }
    }
    __syncthreads();
  }
  float4 bv = *(const float4*)&bias[c0];
  #pragma unroll
  for (int i = 0; i < 8; ++i){
    int grow = row0 + r0 + i;
    if (grow < N){
      float4 v = acc[i];
      v.x += bv.x; v.y += bv.y; v.z += bv.z; v.w += bv.w;
      if (relu){
        v.x = fmaxf(v.x, 0.f); v.y = fmaxf(v.y, 0.f);
        v.z = fmaxf(v.z, 0.f); v.w = fmaxf(v.w, 0.f);
      }
      *(float4*)&out[(size_t)grow*128 + c0] = v;
    }
  }
}

// ---------------- classifier: logits = A@W2 + b2  (128 -> 40) ----------------
__global__ __launch_bounds__(320) void cls_kernel(
    const float* __restrict__ A, const float* __restrict__ W2,
    const float* __restrict__ b2, float* __restrict__ out, int N)
{
  __shared__ float ts[64*128];
  __shared__ float w2s[128*40];
  const int t = threadIdx.x;
  const int row0 = blockIdx.x * 64;
  for (int idx = t; idx < 128*40; idx += 320) w2s[idx] = W2[idx];
  for (int idx = t; idx < 2048; idx += 320){
    int r = idx >> 5, c4 = idx & 31;
    int grow = row0 + r;
    float4 v = make_float4(0.f,0.f,0.f,0.f);
    if (grow < N) v = *(const float4*)&A[(size_t)grow*128 + c4*4];
    *(float4*)&ts[r*128 + c4*4] = v;
  }
  __syncthreads();
  const int c  = t % 40;
  const int rg = t / 40;
  const int r0 = rg * 8;
  float acc[8];
  #pragma unroll
  for (int i = 0; i < 8; ++i) acc[i] = 0.f;
  for (int k4 = 0; k4 < 32; ++k4){
    float w0 = w2s[(k4*4+0)*40 + c];
    float w1 = w2s[(k4*4+1)*40 + c];
    float w2_ = w2s[(k4*4+2)*40 + c];
    float w3 = w2s[(k4*4+3)*40 + c];
    #pragma unroll
    for (int i = 0; i < 8; ++i){
      float4 xv = *(const float4*)&ts[(r0+i)*128 + k4*4];
      acc[i] += xv.x*w0 + xv.y*w1 + xv.z*w2_ + xv.w*w3;
    }
  }
  float bv = b2[c];
  #pragma unroll
  for (int i = 0; i < 8; ++i){
    int grow = row0 + r0 + i;
    if (grow < N) out[(size_t)grow*40 + c] = acc[i] + bv;
  }
}

// ---------------- gather aggregation: one wave per dst node, fused epilogue ----------------
__global__ __launch_bounds__(256) void gather_kernel(
    const int* __restrict__ rowptr, const int* __restrict__ ssrc, const float* __restrict__ sw,
    const float* __restrict__ xl, const float* __restrict__ xr,
    const float* __restrict__ We, const float* __restrict__ att,
    const float* __restrict__ msum, const float* __restrict__ bgat,
    float* __restrict__ hbuf, int N)
{
  const int wid  = threadIdx.x >> 6;
  const int lane = threadIdx.x & 63;
  const int n = blockIdx.x * 4 + wid;
  if (n >= N) return;

  float2 xrv = *(const float2*)&xr[(size_t)n*128 + lane*2];
  float2 wev = *(const float2*)&We[lane*2];
  const int hd = lane >> 4;
  const int m  = lane & 15;
  float a0 = att[hd*32 + 2*m];
  float a1 = att[hd*32 + 2*m + 1];

  float2 num = make_float2(0.f, 0.f);
  float den = 0.f;
  const int beg = rowptr[n], end = rowptr[n + 1];
  const float wm = msum[0];

  for (int i = beg; i <= end; ++i){
    int src; float w;
    if (i < end){ src = ssrc[i]; w = sw[i]; }
    else        { src = n;       w = wm;    }   // self loop
    float2 xlv = *(const float2*)&xl[(size_t)src*128 + lane*2];
    float e0 = xlv.x + xrv.x + w*wev.x;
    float e1 = xlv.y + xrv.y + w*wev.y;
    e0 = e0 > 0.f ? e0 : 0.2f*e0;
    e1 = e1 > 0.f ? e1 : 0.2f*e1;
    float s = e0*a0 + e1*a1;
    s += __shfl_xor(s, 1, 64);
    s += __shfl_xor(s, 2, 64);
    s += __shfl_xor(s, 4, 64);
    s += __shfl_xor(s, 8, 64);   // alpha for this head (softmax shift-invariance: skip max)
    float ex = expf(s);
    num.x = fmaf(ex, xlv.x, num.x);
    num.y = fmaf(ex, xlv.y, num.y);
    den += ex;
  }

  float d = den + 1e-16f;
  float ox = num.x / d + bgat[2*lane];
  float oy = num.y / d + bgat[2*lane + 1];
  ox = ox > 0.f ? ox : expm1f(ox);   // ELU
  oy = oy > 0.f ? oy : expm1f(oy);
  float2 h0v = *(const float2*)&hbuf[(size_t)n*128 + lane*2];
  h0v.x += ox; h0v.y += oy;
  *(float2*)&hbuf[(size_t)n*128 + lane*2] = h0v;   // h = h0 + elu(...)
}

extern "C" void kernel_launch(void* const* d_in, const int* in_sizes, int n_in,
                              void* d_out, int out_size, void* d_ws, size_t ws_size,
                              hipStream_t stream)
{
  const float* x    = (const float*)d_in[0];
  const int*   ei   = (const int*)  d_in[1];
  const float* ew   = (const float*)d_in[2];
  const float* Wpre = (const float*)d_in[3];
  const float* Wl   = (const float*)d_in[4];
  const float* bl   = (const float*)d_in[5];
  const float* Wr   = (const float*)d_in[6];
  const float* br   = (const float*)d_in[7];
  const float* We   = (const float*)d_in[8];
  const float* att  = (const float*)d_in[9];
  const float* bgat = (const float*)d_in[10];
  const float* W1   = (const float*)d_in[11];
  const float* b1   = (const float*)d_in[12];
  const float* W2   = (const float*)d_in[13];
  const float* b2   = (const float*)d_in[14];

  const int N = in_sizes[0] / 128;
  const int E = in_sizes[2];
  const int nb = (N + 255) / 256;

  float* hout   = (float*)d_out;               // [N,128]
  float* logits = hout + (size_t)N*128;        // [N,40]

  // workspace layout
  float* xl     = (float*)d_ws;                // N*128
  float* xr     = xl + (size_t)N*128;          // N*128
  float* sw     = xr + (size_t)N*128;          // E
  int*   ssrc   = (int*)(sw + E);              // E
  int*   rowptr = ssrc + E;                    // N+1
  int*   cursor = rowptr + N + 1;              // N   (doubles as deg)
  float* msum   = (float*)(cursor + N);        // 1   (adjacent to cursor)
  int*   bsum   = (int*)(msum + 1);            // nb
  int*   boff   = bsum + nb;                   // nb
  float* tbuf   = xl;                          // reuse for MLP hidden

  // zero deg(=cursor) + msum in one shot
  hipMemsetAsync(cursor, 0, (size_t)(N + 1) * sizeof(int), stream);

  mean_kernel<<<256, 256, 0, stream>>>(ew, msum, E);
  count_kernel<<<(E + 255)/256, 256, 0, stream>>>(ei, cursor, E);
  scan1_kernel<<<nb, 256, 0, stream>>>(cursor, rowptr, bsum, N);
  scan2_kernel<<<1, 512, 0, stream>>>(bsum, boff, nb);
  scan3_kernel<<<nb, 256, 0, stream>>>(rowptr, boff, N);
  hipMemcpyAsync(cursor, rowptr, (size_t)N * sizeof(int), hipMemcpyDeviceToDevice, stream);
  fill_kernel<<<(E + 255)/256, 256, 0, stream>>>(ei, ew, cursor, ssrc, sw, E);

  fused_pre<<<(N + 63)/64, 256, 0, stream>>>(x, Wpre, Wl, bl, Wr, br, hout, xl, xr, N);
  gather_kernel<<<(N + 3)/4, 256, 0, stream>>>(rowptr, ssrc, sw, xl, xr, We, att, msum, bgat, hout, N);

  gemm128_kernel<<<(N + 63)/64, 256, 0, stream>>>(hout, W1, b1, tbuf, N, 1);
  cls_kernel<<<(N + 63)/64, 320, 0, stream>>>(tbuf, W2, b2, logits, N);
}

// Round 3
// 620.562 us; speedup vs baseline: 3.0398x; 1.2815x over previous
//
#include <hip/hip_runtime.h>

typedef __attribute__((ext_vector_type(8))) short short8;
typedef __attribute__((ext_vector_type(16))) float f32x16;

static __device__ __forceinline__ unsigned short f2bf(float f){
  unsigned u = __float_as_uint(f);
  unsigned r = u + 0x7fffu + ((u >> 16) & 1u);
  return (unsigned short)(r >> 16);
}
static __device__ __forceinline__ float bf2f(unsigned short h){
  return __uint_as_float(((unsigned)h) << 16);
}

// ---------------- mean of edge weights ----------------
__global__ void mean_kernel(const float* __restrict__ ew, float* __restrict__ msum, int E){
  float s = 0.f;
  for (int i = blockIdx.x*blockDim.x + threadIdx.x; i < E; i += gridDim.x*blockDim.x) s += ew[i];
  for (int d = 32; d > 0; d >>= 1) s += __shfl_down(s, d, 64);
  __shared__ float ps[4];
  int lane = threadIdx.x & 63, w = threadIdx.x >> 6;
  if (lane == 0) ps[w] = s;
  __syncthreads();
  if (threadIdx.x == 0){
    float tot = ps[0] + ps[1] + ps[2] + ps[3];
    atomicAdd(msum, tot / (float)E);
  }
}

// ---------------- weight transpose + hi/lo bf16 split:  Wt[c][k] = W[k][c] ----------------
__global__ void wsplit(const float* __restrict__ W, int ncol,
                       unsigned short* __restrict__ hi, unsigned short* __restrict__ lo, int nelem){
  int i = blockIdx.x*256 + threadIdx.x;
  if (i >= nelem) return;
  int c = i >> 7, k = i & 127;
  float v = W[(size_t)k*ncol + c];
  unsigned short h = f2bf(v);
  hi[i] = h;
  lo[i] = f2bf(v - bf2f(h));
}

// ---------------- CSR build ----------------
__global__ void count_kernel(const int* __restrict__ ei, int* __restrict__ deg, int E){
  int e = blockIdx.x*256 + threadIdx.x;
  if (e < E) atomicAdd(&deg[ei[E + e]], 1);
}

__global__ __launch_bounds__(256) void scan1_kernel(const int* __restrict__ deg, int* __restrict__ rowptr,
                                                    int* __restrict__ bsum, int N){
  __shared__ int s[256];
  int i = blockIdx.x*256 + threadIdx.x;
  int v = (i < N) ? deg[i] : 0;
  s[threadIdx.x] = v;
  __syncthreads();
  for (int off = 1; off < 256; off <<= 1){
    int t = (threadIdx.x >= off) ? s[threadIdx.x - off] : 0;
    __syncthreads();
    s[threadIdx.x] += t;
    __syncthreads();
  }
  if (i < N) rowptr[i + 1] = s[threadIdx.x];
  if (threadIdx.x == 255) bsum[blockIdx.x] = s[255];
}

__global__ __launch_bounds__(512) void scan2_kernel(const int* __restrict__ bsum, int* __restrict__ boff, int nb){
  __shared__ int s[512];
  int v = (threadIdx.x < nb) ? bsum[threadIdx.x] : 0;
  s[threadIdx.x] = v;
  __syncthreads();
  for (int off = 1; off < 512; off <<= 1){
    int t = (threadIdx.x >= off) ? s[threadIdx.x - off] : 0;
    __syncthreads();
    s[threadIdx.x] += t;
    __syncthreads();
  }
  if (threadIdx.x < nb) boff[threadIdx.x] = s[threadIdx.x] - v;
}

__global__ void scan3_kernel(int* __restrict__ rowptr, const int* __restrict__ boff, int N){
  int i = blockIdx.x*256 + threadIdx.x;
  if (i == 0) rowptr[0] = 0;
  if (i < N) rowptr[i + 1] += boff[i >> 8];
}

__global__ void fill_kernel(const int* __restrict__ ei, const float* __restrict__ ew,
                            int* __restrict__ cursor, int* __restrict__ ssrc,
                            float* __restrict__ sw, int E){
  int e = blockIdx.x*256 + threadIdx.x;
  if (e >= E) return;
  int dst = ei[E + e];
  int pos = atomicAdd(&cursor[dst], 1);
  ssrc[pos] = ei[e];
  sw[pos]   = ew[e];
}

// ---------------- MFMA GEMM: out[N,ncols] = act(A[N,128] @ W + bias) ----------------
// 3-pass split bf16 (fp32-exact to ~2^-18): acc += Ahi*Whi + Alo*Whi + Ahi*Wlo.
// Block: 64 rows x 128 cols, 4 waves x 32 cols, B(hi/lo) in registers, A tile in LDS.
template<bool BIAS, bool RELU>
__global__ __launch_bounds__(256) void mgemm(
    const float* __restrict__ A,
    const unsigned short* __restrict__ Bhi, const unsigned short* __restrict__ Blo,
    const float* __restrict__ bias, float* __restrict__ out, int N, int ncols)
{
  __shared__ short alds[2*64*128];   // hi plane [0,8192), lo plane [8192,16384)
  const int t = threadIdx.x;
  const int row0 = blockIdx.x * 64;

  // stage A tile (64x128 fp32 -> split bf16, slot-xor swizzle on 8-elem groups)
  for (int g = t; g < 1024; g += 256){
    int r = g >> 4, k8 = g & 15;
    int grow = row0 + r;
    float4 p0, p1;
    if (grow < N){
      const float* ap = A + (size_t)grow*128 + k8*8;
      p0 = *(const float4*)ap;
      p1 = *(const float4*)(ap + 4);
    } else {
      p0 = make_float4(0.f,0.f,0.f,0.f); p1 = p0;
    }
    float vv[8] = {p0.x,p0.y,p0.z,p0.w,p1.x,p1.y,p1.z,p1.w};
    short8 hv, lv;
    #pragma unroll
    for (int j = 0; j < 8; ++j){
      unsigned short h = f2bf(vv[j]);
      hv[j] = (short)h;
      lv[j] = (short)f2bf(vv[j] - bf2f(h));
    }
    int slot = k8 ^ (r & 15);
    *(short8*)&alds[r*128 + slot*8] = hv;
    *(short8*)&alds[8192 + r*128 + slot*8] = lv;
  }
  __syncthreads();

  const int lane = t & 63, w = t >> 6;
  const int c0 = w * 32;
  if (c0 >= ncols) return;              // dead col-waves (cls): done after staging
  const int cl = lane & 31, kg = lane >> 5;
  const int col = c0 + cl;
  const bool cok = col < ncols;

  // B fragments in registers: Wt[col][k], 8 k-steps of 16 (8 bf16/lane each)
  short8 bh[8], bl8[8];
  #pragma unroll
  for (int ks = 0; ks < 8; ++ks){
    if (cok){
      size_t off = (size_t)col*128 + ks*16 + kg*8;
      bh[ks]  = *(const short8*)(Bhi + off);
      bl8[ks] = *(const short8*)(Blo + off);
    } else {
      #pragma unroll
      for (int j = 0; j < 8; ++j){ bh[ks][j] = 0; bl8[ks][j] = 0; }
    }
  }

  f32x16 acc0, acc1;
  #pragma unroll
  for (int i = 0; i < 16; ++i){ acc0[i] = 0.f; acc1[i] = 0.f; }

  const int r0 = cl;
  const int sx = r0 & 15;
  #pragma unroll
  for (int ks = 0; ks < 8; ++ks){
    int k8 = ks*2 + kg;
    const short* a0 = &alds[r0*128 + (k8 ^ sx)*8];
    const short* a1 = &alds[(r0+32)*128 + (k8 ^ sx)*8];
    short8 a0h = *(const short8*)a0;
    short8 a0l = *(const short8*)(a0 + 8192);
    short8 a1h = *(const short8*)a1;
    short8 a1l = *(const short8*)(a1 + 8192);
    acc0 = __builtin_amdgcn_mfma_f32_32x32x16_bf16(a0h, bh[ks],  acc0, 0,0,0);
    acc1 = __builtin_amdgcn_mfma_f32_32x32x16_bf16(a1h, bh[ks],  acc1, 0,0,0);
    acc0 = __builtin_amdgcn_mfma_f32_32x32x16_bf16(a0l, bh[ks],  acc0, 0,0,0);
    acc1 = __builtin_amdgcn_mfma_f32_32x32x16_bf16(a1l, bh[ks],  acc1, 0,0,0);
    acc0 = __builtin_amdgcn_mfma_f32_32x32x16_bf16(a0h, bl8[ks], acc0, 0,0,0);
    acc1 = __builtin_amdgcn_mfma_f32_32x32x16_bf16(a1h, bl8[ks], acc1, 0,0,0);
  }

  if (!cok) return;                     // no barriers below: divergent return ok
  float bv = BIAS ? bias[col] : 0.f;

  #pragma unroll
  for (int rt = 0; rt < 2; ++rt){
    const f32x16& ac = rt ? acc1 : acc0;
    #pragma unroll
    for (int reg = 0; reg < 16; ++reg){
      int row = rt*32 + (reg & 3) + 8*(reg >> 2) + 4*kg;   // verified C/D layout (m74/m101)
      int grow = row0 + row;
      if (grow < N){
        float v = ac[reg] + bv;
        if (RELU) v = fmaxf(v, 0.f);
        out[(size_t)grow*ncols + col] = v;
      }
    }
  }
}

// ---------------- gather aggregation: one wave per dst node, fused epilogue ----------------
__global__ __launch_bounds__(256) void gather_kernel(
    const int* __restrict__ rowptr, const int* __restrict__ ssrc, const float* __restrict__ sw,
    const float* __restrict__ xl, const float* __restrict__ xr,
    const float* __restrict__ We, const float* __restrict__ att,
    const float* __restrict__ msum, const float* __restrict__ bgat,
    float* __restrict__ hbuf, int N)
{
  const int wid  = threadIdx.x >> 6;
  const int lane = threadIdx.x & 63;
  const int n = blockIdx.x * 4 + wid;
  if (n >= N) return;

  float2 xrv = *(const float2*)&xr[(size_t)n*128 + lane*2];
  float2 wev = *(const float2*)&We[lane*2];
  const int hd = lane >> 4;
  const int m  = lane & 15;
  float a0 = att[hd*32 + 2*m];
  float a1 = att[hd*32 + 2*m + 1];

  float2 num = make_float2(0.f, 0.f);
  float den = 0.f;
  const int beg = rowptr[n], end = rowptr[n + 1];
  const float wm = msum[0];

  for (int i = beg; i <= end; ++i){
    int src; float w;
    if (i < end){ src = ssrc[i]; w = sw[i]; }
    else        { src = n;       w = wm;    }   // self loop
    float2 xlv = *(const float2*)&xl[(size_t)src*128 + lane*2];
    float e0 = xlv.x + xrv.x + w*wev.x;
    float e1 = xlv.y + xrv.y + w*wev.y;
    e0 = e0 > 0.f ? e0 : 0.2f*e0;
    e1 = e1 > 0.f ? e1 : 0.2f*e1;
    float s = e0*a0 + e1*a1;
    s += __shfl_xor(s, 1, 64);
    s += __shfl_xor(s, 2, 64);
    s += __shfl_xor(s, 4, 64);
    s += __shfl_xor(s, 8, 64);   // alpha for this head (softmax shift-invariance: skip max)
    float ex = expf(s);
    num.x = fmaf(ex, xlv.x, num.x);
    num.y = fmaf(ex, xlv.y, num.y);
    den += ex;
  }

  float d = den + 1e-16f;
  float ox = num.x / d + bgat[2*lane];
  float oy = num.y / d + bgat[2*lane + 1];
  ox = ox > 0.f ? ox : expm1f(ox);   // ELU
  oy = oy > 0.f ? oy : expm1f(oy);
  float2 h0v = *(const float2*)&hbuf[(size_t)n*128 + lane*2];
  h0v.x += ox; h0v.y += oy;
  *(float2*)&hbuf[(size_t)n*128 + lane*2] = h0v;   // h = h0 + elu(...)
}

extern "C" void kernel_launch(void* const* d_in, const int* in_sizes, int n_in,
                              void* d_out, int out_size, void* d_ws, size_t ws_size,
                              hipStream_t stream)
{
  const float* x    = (const float*)d_in[0];
  const int*   ei   = (const int*)  d_in[1];
  const float* ew   = (const float*)d_in[2];
  const float* Wpre = (const float*)d_in[3];
  const float* Wl   = (const float*)d_in[4];
  const float* bl   = (const float*)d_in[5];
  const float* Wr   = (const float*)d_in[6];
  const float* br   = (const float*)d_in[7];
  const float* We   = (const float*)d_in[8];
  const float* att  = (const float*)d_in[9];
  const float* bgat = (const float*)d_in[10];
  const float* W1   = (const float*)d_in[11];
  const float* b1   = (const float*)d_in[12];
  const float* W2   = (const float*)d_in[13];
  const float* b2   = (const float*)d_in[14];

  const int N = in_sizes[0] / 128;
  const int E = in_sizes[2];
  const int nb = (N + 255) / 256;

  float* hout   = (float*)d_out;               // [N,128]
  float* logits = hout + (size_t)N*128;        // [N,40]

  // workspace layout
  float* xl     = (float*)d_ws;                // N*128
  float* xr     = xl + (size_t)N*128;          // N*128
  float* sw     = xr + (size_t)N*128;          // E
  int*   ssrc   = (int*)(sw + E);              // E
  int*   rowptr = ssrc + E;                    // N+1
  int*   cursor = rowptr + N + 1;              // N   (doubles as deg)
  float* msum   = (float*)(cursor + N);        // 1
  int*   bsum   = (int*)(msum + 1);            // nb
  int*   boff   = bsum + nb;                   // nb
  unsigned short* wsp = (unsigned short*)(((uintptr_t)(boff + nb) + 15) & ~(uintptr_t)15);
  unsigned short* WpreT_hi = wsp;              // 128*128 each
  unsigned short* WpreT_lo = WpreT_hi + 16384;
  unsigned short* WlT_hi   = WpreT_lo + 16384;
  unsigned short* WlT_lo   = WlT_hi   + 16384;
  unsigned short* WrT_hi   = WlT_lo   + 16384;
  unsigned short* WrT_lo   = WrT_hi   + 16384;
  unsigned short* W1T_hi   = WrT_lo   + 16384;
  unsigned short* W1T_lo   = W1T_hi   + 16384;
  unsigned short* W2T_hi   = W1T_lo   + 16384; // 40*128 each
  unsigned short* W2T_lo   = W2T_hi   + 5120;
  float* tbuf = xl;                            // reuse after gather

  // zero deg(=cursor) + msum in one shot
  hipMemsetAsync(cursor, 0, (size_t)(N + 1) * sizeof(int), stream);

  mean_kernel<<<256, 256, 0, stream>>>(ew, msum, E);

  wsplit<<<64, 256, 0, stream>>>(Wpre, 128, WpreT_hi, WpreT_lo, 16384);
  wsplit<<<64, 256, 0, stream>>>(Wl,   128, WlT_hi,   WlT_lo,   16384);
  wsplit<<<64, 256, 0, stream>>>(Wr,   128, WrT_hi,   WrT_lo,   16384);
  wsplit<<<64, 256, 0, stream>>>(W1,   128, W1T_hi,   W1T_lo,   16384);
  wsplit<<<20, 256, 0, stream>>>(W2,    40, W2T_hi,   W2T_lo,    5120);

  count_kernel<<<(E + 255)/256, 256, 0, stream>>>(ei, cursor, E);
  scan1_kernel<<<nb, 256, 0, stream>>>(cursor, rowptr, bsum, N);
  scan2_kernel<<<1, 512, 0, stream>>>(bsum, boff, nb);
  scan3_kernel<<<nb, 256, 0, stream>>>(rowptr, boff, N);
  hipMemcpyAsync(cursor, rowptr, (size_t)N * sizeof(int), hipMemcpyDeviceToDevice, stream);
  fill_kernel<<<(E + 255)/256, 256, 0, stream>>>(ei, ew, cursor, ssrc, sw, E);

  const int gg = (N + 63) / 64;
  mgemm<false,false><<<gg, 256, 0, stream>>>(x,    WpreT_hi, WpreT_lo, nullptr, hout,   N, 128);
  mgemm<true, false><<<gg, 256, 0, stream>>>(hout, WlT_hi,   WlT_lo,   bl,      xl,     N, 128);
  mgemm<true, false><<<gg, 256, 0, stream>>>(hout, WrT_hi,   WrT_lo,   br,      xr,     N, 128);

  gather_kernel<<<(N + 3)/4, 256, 0, stream>>>(rowptr, ssrc, sw, xl, xr, We, att, msum, bgat, hout, N);

  mgemm<true, true ><<<gg, 256, 0, stream>>>(hout, W1T_hi, W1T_lo, b1, tbuf,   N, 128);
  mgemm<true, false><<<gg, 256, 0, stream>>>(tbuf, W2T_hi, W2T_lo, b2, logits, N, 40);
}

// Round 4
// 522.702 us; speedup vs baseline: 3.6089x; 1.1872x over previous
//
#include <hip/hip_runtime.h>

typedef __attribute__((ext_vector_type(8))) short short8;
typedef __attribute__((ext_vector_type(16))) float f32x16;

#if __has_builtin(__builtin_amdgcn_exp2f)
#define EXP2(x) __builtin_amdgcn_exp2f(x)
#else
#define EXP2(x) exp2f(x)
#endif

static __device__ __forceinline__ unsigned short f2bf(float f){
  unsigned u = __float_as_uint(f);
  unsigned r = u + 0x7fffu + ((u >> 16) & 1u);
  return (unsigned short)(r >> 16);
}
static __device__ __forceinline__ float bf2f(unsigned short h){
  return __uint_as_float(((unsigned)h) << 16);
}

// ---------------- mean of edge weights ----------------
__global__ void mean_kernel(const float* __restrict__ ew, float* __restrict__ msum, int E){
  float s = 0.f;
  for (int i = blockIdx.x*blockDim.x + threadIdx.x; i < E; i += gridDim.x*blockDim.x) s += ew[i];
  for (int d = 32; d > 0; d >>= 1) s += __shfl_down(s, d, 64);
  __shared__ float ps[4];
  int lane = threadIdx.x & 63, w = threadIdx.x >> 6;
  if (lane == 0) ps[w] = s;
  __syncthreads();
  if (threadIdx.x == 0){
    float tot = ps[0] + ps[1] + ps[2] + ps[3];
    atomicAdd(msum, tot / (float)E);
  }
}

// ---------------- weight transpose + hi/lo bf16 split:  Wt[c][k] = W[k][c] ----------------
__global__ void wsplit(const float* __restrict__ W, int ncol,
                       unsigned short* __restrict__ hi, unsigned short* __restrict__ lo, int nelem){
  int i = blockIdx.x*256 + threadIdx.x;
  if (i >= nelem) return;
  int c = i >> 7, k = i & 127;
  float v = W[(size_t)k*ncol + c];
  unsigned short h = f2bf(v);
  hi[i] = h;
  lo[i] = f2bf(v - bf2f(h));
}

// combined [Wl|Wr] transpose+split: 256 cols
__global__ void wsplit_lr(const float* __restrict__ Wl, const float* __restrict__ Wr,
                          unsigned short* __restrict__ hi, unsigned short* __restrict__ lo){
  int i = blockIdx.x*256 + threadIdx.x;   // 256*128 elems
  if (i >= 256*128) return;
  int c = i >> 7, k = i & 127;
  float v = (c < 128) ? Wl[(size_t)k*128 + c] : Wr[(size_t)k*128 + (c-128)];
  unsigned short h = f2bf(v);
  hi[i] = h;
  lo[i] = f2bf(v - bf2f(h));
}

__global__ void catbias(const float* __restrict__ bl, const float* __restrict__ br,
                        float* __restrict__ o){
  int i = threadIdx.x;
  o[i] = (i < 128) ? bl[i] : br[i-128];
}

// ---------------- CSR build ----------------
__global__ void count_kernel(const int* __restrict__ ei, int* __restrict__ deg, int E){
  int e = blockIdx.x*256 + threadIdx.x;
  if (e < E) atomicAdd(&deg[ei[E + e]], 1);
}

__global__ __launch_bounds__(256) void scan1_kernel(const int* __restrict__ deg, int* __restrict__ rowptr,
                                                    int* __restrict__ bsum, int N){
  __shared__ int s[256];
  int i = blockIdx.x*256 + threadIdx.x;
  int v = (i < N) ? deg[i] : 0;
  s[threadIdx.x] = v;
  __syncthreads();
  for (int off = 1; off < 256; off <<= 1){
    int t = (threadIdx.x >= off) ? s[threadIdx.x - off] : 0;
    __syncthreads();
    s[threadIdx.x] += t;
    __syncthreads();
  }
  if (i < N) rowptr[i + 1] = s[threadIdx.x];
  if (threadIdx.x == 255) bsum[blockIdx.x] = s[255];
}

__global__ __launch_bounds__(512) void scan2_kernel(const int* __restrict__ bsum, int* __restrict__ boff, int nb){
  __shared__ int s[512];
  int v = (threadIdx.x < nb) ? bsum[threadIdx.x] : 0;
  s[threadIdx.x] = v;
  __syncthreads();
  for (int off = 1; off < 512; off <<= 1){
    int t = (threadIdx.x >= off) ? s[threadIdx.x - off] : 0;
    __syncthreads();
    s[threadIdx.x] += t;
    __syncthreads();
  }
  if (threadIdx.x < nb) boff[threadIdx.x] = s[threadIdx.x] - v;
}

__global__ void scan3_kernel(int* __restrict__ rowptr, const int* __restrict__ boff, int N){
  int i = blockIdx.x*256 + threadIdx.x;
  if (i == 0) rowptr[0] = 0;
  if (i < N) rowptr[i + 1] += boff[i >> 8];
}

__global__ void fill_kernel(const int* __restrict__ ei, const float* __restrict__ ew,
                            int* __restrict__ cursor, int2* __restrict__ erec, int E){
  int e = blockIdx.x*256 + threadIdx.x;
  if (e >= E) return;
  int dst = ei[E + e];
  int pos = atomicAdd(&cursor[dst], 1);
  erec[pos] = make_int2(ei[e], __float_as_int(ew[e]));
}

// ---------------- MFMA GEMM (4-wave, up to 128 cols) ----------------
template<bool BIAS, bool RELU>
__global__ __launch_bounds__(256) void mgemm(
    const float* __restrict__ A,
    const unsigned short* __restrict__ Bhi, const unsigned short* __restrict__ Blo,
    const float* __restrict__ bias, float* __restrict__ out, int N, int ncols)
{
  __shared__ short alds[2*64*128];
  const int t = threadIdx.x;
  const int row0 = blockIdx.x * 64;

  for (int g = t; g < 1024; g += 256){
    int r = g >> 4, k8 = g & 15;
    int grow = row0 + r;
    float4 p0, p1;
    if (grow < N){
      const float* ap = A + (size_t)grow*128 + k8*8;
      p0 = *(const float4*)ap;
      p1 = *(const float4*)(ap + 4);
    } else {
      p0 = make_float4(0.f,0.f,0.f,0.f); p1 = p0;
    }
    float vv[8] = {p0.x,p0.y,p0.z,p0.w,p1.x,p1.y,p1.z,p1.w};
    short8 hv, lv;
    #pragma unroll
    for (int j = 0; j < 8; ++j){
      unsigned short h = f2bf(vv[j]);
      hv[j] = (short)h;
      lv[j] = (short)f2bf(vv[j] - bf2f(h));
    }
    int slot = k8 ^ (r & 15);
    *(short8*)&alds[r*128 + slot*8] = hv;
    *(short8*)&alds[8192 + r*128 + slot*8] = lv;
  }
  __syncthreads();

  const int lane = t & 63, w = t >> 6;
  const int c0 = w * 32;
  if (c0 >= ncols) return;
  const int cl = lane & 31, kg = lane >> 5;
  const int col = c0 + cl;
  const bool cok = col < ncols;

  short8 bh[8], bl8[8];
  #pragma unroll
  for (int ks = 0; ks < 8; ++ks){
    if (cok){
      size_t off = (size_t)col*128 + ks*16 + kg*8;
      bh[ks]  = *(const short8*)(Bhi + off);
      bl8[ks] = *(const short8*)(Blo + off);
    } else {
      #pragma unroll
      for (int j = 0; j < 8; ++j){ bh[ks][j] = 0; bl8[ks][j] = 0; }
    }
  }

  f32x16 acc0, acc1;
  #pragma unroll
  for (int i = 0; i < 16; ++i){ acc0[i] = 0.f; acc1[i] = 0.f; }

  const int r0 = cl;
  const int sx = r0 & 15;
  #pragma unroll
  for (int ks = 0; ks < 8; ++ks){
    int k8 = ks*2 + kg;
    const short* a0 = &alds[r0*128 + (k8 ^ sx)*8];
    const short* a1 = &alds[(r0+32)*128 + (k8 ^ sx)*8];
    short8 a0h = *(const short8*)a0;
    short8 a0l = *(const short8*)(a0 + 8192);
    short8 a1h = *(const short8*)a1;
    short8 a1l = *(const short8*)(a1 + 8192);
    acc0 = __builtin_amdgcn_mfma_f32_32x32x16_bf16(a0h, bh[ks],  acc0, 0,0,0);
    acc1 = __builtin_amdgcn_mfma_f32_32x32x16_bf16(a1h, bh[ks],  acc1, 0,0,0);
    acc0 = __builtin_amdgcn_mfma_f32_32x32x16_bf16(a0l, bh[ks],  acc0, 0,0,0);
    acc1 = __builtin_amdgcn_mfma_f32_32x32x16_bf16(a1l, bh[ks],  acc1, 0,0,0);
    acc0 = __builtin_amdgcn_mfma_f32_32x32x16_bf16(a0h, bl8[ks], acc0, 0,0,0);
    acc1 = __builtin_amdgcn_mfma_f32_32x32x16_bf16(a1h, bl8[ks], acc1, 0,0,0);
  }

  if (!cok) return;
  float bv = BIAS ? bias[col] : 0.f;

  #pragma unroll
  for (int rt = 0; rt < 2; ++rt){
    const f32x16& ac = rt ? acc1 : acc0;
    #pragma unroll
    for (int reg = 0; reg < 16; ++reg){
      int row = rt*32 + (reg & 3) + 8*(reg >> 2) + 4*kg;
      int grow = row0 + row;
      if (grow < N){
        float v = ac[reg] + bv;
        if (RELU) v = fmaxf(v, 0.f);
        out[(size_t)grow*ncols + col] = v;
      }
    }
  }
}

// ---------------- MFMA GEMM (8-wave, 256 cols): xlr = hout @ [Wl|Wr] + [bl|br] ----------------
__global__ __launch_bounds__(512) void mgemm512(
    const float* __restrict__ A,
    const unsigned short* __restrict__ Bhi, const unsigned short* __restrict__ Blo,
    const float* __restrict__ bias, float* __restrict__ out, int N)
{
  __shared__ short alds[2*64*128];
  const int t = threadIdx.x;
  const int row0 = blockIdx.x * 64;

  for (int g = t; g < 1024; g += 512){
    int r = g >> 4, k8 = g & 15;
    int grow = row0 + r;
    float4 p0, p1;
    if (grow < N){
      const float* ap = A + (size_t)grow*128 + k8*8;
      p0 = *(const float4*)ap;
      p1 = *(const float4*)(ap + 4);
    } else {
      p0 = make_float4(0.f,0.f,0.f,0.f); p1 = p0;
    }
    float vv[8] = {p0.x,p0.y,p0.z,p0.w,p1.x,p1.y,p1.z,p1.w};
    short8 hv, lv;
    #pragma unroll
    for (int j = 0; j < 8; ++j){
      unsigned short h = f2bf(vv[j]);
      hv[j] = (short)h;
      lv[j] = (short)f2bf(vv[j] - bf2f(h));
    }
    int slot = k8 ^ (r & 15);
    *(short8*)&alds[r*128 + slot*8] = hv;
    *(short8*)&alds[8192 + r*128 + slot*8] = lv;
  }
  __syncthreads();

  const int lane = t & 63, w = t >> 6;
  const int c0 = w * 32;
  const int cl = lane & 31, kg = lane >> 5;
  const int col = c0 + cl;

  short8 bh[8], bl8[8];
  #pragma unroll
  for (int ks = 0; ks < 8; ++ks){
    size_t off = (size_t)col*128 + ks*16 + kg*8;
    bh[ks]  = *(const short8*)(Bhi + off);
    bl8[ks] = *(const short8*)(Blo + off);
  }

  f32x16 acc0, acc1;
  #pragma unroll
  for (int i = 0; i < 16; ++i){ acc0[i] = 0.f; acc1[i] = 0.f; }

  const int r0 = cl;
  const int sx = r0 & 15;
  #pragma unroll
  for (int ks = 0; ks < 8; ++ks){
    int k8 = ks*2 + kg;
    const short* a0 = &alds[r0*128 + (k8 ^ sx)*8];
    const short* a1 = &alds[(r0+32)*128 + (k8 ^ sx)*8];
    short8 a0h = *(const short8*)a0;
    short8 a0l = *(const short8*)(a0 + 8192);
    short8 a1h = *(const short8*)a1;
    short8 a1l = *(const short8*)(a1 + 8192);
    acc0 = __builtin_amdgcn_mfma_f32_32x32x16_bf16(a0h, bh[ks],  acc0, 0,0,0);
    acc1 = __builtin_amdgcn_mfma_f32_32x32x16_bf16(a1h, bh[ks],  acc1, 0,0,0);
    acc0 = __builtin_amdgcn_mfma_f32_32x32x16_bf16(a0l, bh[ks],  acc0, 0,0,0);
    acc1 = __builtin_amdgcn_mfma_f32_32x32x16_bf16(a1l, bh[ks],  acc1, 0,0,0);
    acc0 = __builtin_amdgcn_mfma_f32_32x32x16_bf16(a0h, bl8[ks], acc0, 0,0,0);
    acc1 = __builtin_amdgcn_mfma_f32_32x32x16_bf16(a1h, bl8[ks], acc1, 0,0,0);
  }

  float bv = bias[col];
  #pragma unroll
  for (int rt = 0; rt < 2; ++rt){
    const f32x16& ac = rt ? acc1 : acc0;
    #pragma unroll
    for (int reg = 0; reg < 16; ++reg){
      int row = rt*32 + (reg & 3) + 8*(reg >> 2) + 4*kg;
      int grow = row0 + row;
      if (grow < N) out[(size_t)grow*256 + col] = ac[reg] + bv;
    }
  }
}

// ---------------- gather: 4 edges/wave x 16 lanes/edge, fused epilogue ----------------
// xlr[n][0..127] = xl, xlr[n][128..255] = xr
__global__ __launch_bounds__(256) void gather_kernel(
    const int* __restrict__ rowptr, const int2* __restrict__ erec,
    const float* __restrict__ xlr,
    const float* __restrict__ We, const float* __restrict__ att,
    const float* __restrict__ msum, const float* __restrict__ bgat,
    float* __restrict__ hbuf, int N)
{
  const int wid  = threadIdx.x >> 6;
  const int lane = threadIdx.x & 63;
  const int n = blockIdx.x * 4 + wid;
  if (n >= N) return;

  const int g   = lane >> 4;      // edge slot 0..3
  const int l   = lane & 15;      // channel sub-lane: channels [l*8, l*8+8)
  const int ch0 = l * 8;

  // per-node constants (8 channels per lane)
  float xrv[8], wev[8], at6[8], at4[8];
  {
    float4 q0 = *(const float4*)&xlr[(size_t)n*256 + 128 + ch0];
    float4 q1 = *(const float4*)&xlr[(size_t)n*256 + 128 + ch0 + 4];
    float4 w0 = *(const float4*)&We[ch0];
    float4 w1 = *(const float4*)&We[ch0+4];
    float4 a0 = *(const float4*)&att[ch0];     // att flat [4*32]: index == channel
    float4 a1 = *(const float4*)&att[ch0+4];
    const float L2E = 1.4426950408889634f;
    float qv[8] = {q0.x,q0.y,q0.z,q0.w,q1.x,q1.y,q1.z,q1.w};
    float wv[8] = {w0.x,w0.y,w0.z,w0.w,w1.x,w1.y,w1.z,w1.w};
    float av[8] = {a0.x,a0.y,a0.z,a0.w,a1.x,a1.y,a1.z,a1.w};
    #pragma unroll
    for (int j = 0; j < 8; ++j){
      xrv[j] = qv[j]; wev[j] = wv[j];
      at6[j] = av[j]*0.6f*L2E;    // lrelu(z) = 0.6z + 0.4|z|, fold log2(e) for exp2
      at4[j] = av[j]*0.4f*L2E;
    }
  }

  float num[8];
  #pragma unroll
  for (int j = 0; j < 8; ++j) num[j] = 0.f;
  float den = 0.f;

  const int beg = rowptr[n], end = rowptr[n + 1];   // real edges [beg,end), self at 'end'
  const float wm = msum[0];

  for (int base = beg; base <= end; base += 4){
    int i = base + g;
    int src = n; float w = wm;
    if (i < end){ int2 r = erec[i]; src = r.x; w = __int_as_float(r.y); }
    const bool act = (i <= end);

    float4 p0 = *(const float4*)&xlr[(size_t)src*256 + ch0];
    float4 p1 = *(const float4*)&xlr[(size_t)src*256 + ch0 + 4];
    float xlv[8] = {p0.x,p0.y,p0.z,p0.w,p1.x,p1.y,p1.z,p1.w};

    float p = 0.f;
    #pragma unroll
    for (int j = 0; j < 8; ++j){
      float z = fmaf(w, wev[j], xlv[j] + xrv[j]);
      p = fmaf(at6[j], z, p);
      p = fmaf(at4[j], fabsf(z), p);
    }
    p += __shfl_xor(p, 1, 64);
    p += __shfl_xor(p, 2, 64);      // per-head alpha*log2e on the 4 lanes of this head
    float ex = act ? EXP2(p) : 0.f;
    den += ex;
    #pragma unroll
    for (int j = 0; j < 8; ++j) num[j] = fmaf(ex, xlv[j], num[j]);
  }

  // reduce across the 4 edge-slots (lanes l, l+16, l+32, l+48)
  #pragma unroll
  for (int j = 0; j < 8; ++j){
    num[j] += __shfl_xor(num[j], 16, 64);
    num[j] += __shfl_xor(num[j], 32, 64);
  }
  den += __shfl_xor(den, 16, 64);
  den += __shfl_xor(den, 32, 64);

  if (g == 0){
    float inv = 1.f / (den + 1e-16f);
    float o[8];
    #pragma unroll
    for (int j = 0; j < 8; ++j){
      float v = num[j]*inv + bgat[ch0+j];
      o[j] = v > 0.f ? v : expm1f(v);   // ELU
    }
    float4 h0a = *(const float4*)&hbuf[(size_t)n*128 + ch0];
    float4 h0b = *(const float4*)&hbuf[(size_t)n*128 + ch0 + 4];
    h0a.x += o[0]; h0a.y += o[1]; h0a.z += o[2]; h0a.w += o[3];
    h0b.x += o[4]; h0b.y += o[5]; h0b.z += o[6]; h0b.w += o[7];
    *(float4*)&hbuf[(size_t)n*128 + ch0]     = h0a;
    *(float4*)&hbuf[(size_t)n*128 + ch0 + 4] = h0b;
  }
}

extern "C" void kernel_launch(void* const* d_in, const int* in_sizes, int n_in,
                              void* d_out, int out_size, void* d_ws, size_t ws_size,
                              hipStream_t stream)
{
  const float* x    = (const float*)d_in[0];
  const int*   ei   = (const int*)  d_in[1];
  const float* ew   = (const float*)d_in[2];
  const float* Wpre = (const float*)d_in[3];
  const float* Wl   = (const float*)d_in[4];
  const float* bl   = (const float*)d_in[5];
  const float* Wr   = (const float*)d_in[6];
  const float* br   = (const float*)d_in[7];
  const float* We   = (const float*)d_in[8];
  const float* att  = (const float*)d_in[9];
  const float* bgat = (const float*)d_in[10];
  const float* W1   = (const float*)d_in[11];
  const float* b1   = (const float*)d_in[12];
  const float* W2   = (const float*)d_in[13];
  const float* b2   = (const float*)d_in[14];

  const int N = in_sizes[0] / 128;
  const int E = in_sizes[2];
  const int nb = (N + 255) / 256;

  float* hout   = (float*)d_out;               // [N,128]
  float* logits = hout + (size_t)N*128;        // [N,40]

  // workspace layout
  float* xlr    = (float*)d_ws;                // N*256 (xl | xr interleaved per row)
  int2*  erec   = (int2*)(xlr + (size_t)N*256);// E records (src, w)
  int*   rowptr = (int*)(erec + E);            // N+1
  int*   cursor = rowptr + N + 1;              // N (doubles as deg)
  float* msum   = (float*)(cursor + N);        // 1
  int*   bsum   = (int*)(msum + 1);            // nb
  int*   boff   = bsum + nb;                   // nb
  float* bcat   = (float*)(boff + nb);         // 256
  unsigned short* wsp = (unsigned short*)(((uintptr_t)(bcat + 256) + 15) & ~(uintptr_t)15);
  unsigned short* WpreT_hi = wsp;              // 128*128
  unsigned short* WpreT_lo = WpreT_hi + 16384;
  unsigned short* WlrT_hi  = WpreT_lo + 16384; // 256*128
  unsigned short* WlrT_lo  = WlrT_hi  + 32768;
  unsigned short* W1T_hi   = WlrT_lo  + 32768; // 128*128
  unsigned short* W1T_lo   = W1T_hi   + 16384;
  unsigned short* W2T_hi   = W1T_lo   + 16384; // 40*128
  unsigned short* W2T_lo   = W2T_hi   + 5120;
  float* tbuf = xlr;                           // reuse after gather (N*128)

  hipMemsetAsync(cursor, 0, (size_t)(N + 1) * sizeof(int), stream);

  mean_kernel<<<256, 256, 0, stream>>>(ew, msum, E);

  wsplit<<<64, 256, 0, stream>>>(Wpre, 128, WpreT_hi, WpreT_lo, 16384);
  wsplit_lr<<<128, 256, 0, stream>>>(Wl, Wr, WlrT_hi, WlrT_lo);
  wsplit<<<64, 256, 0, stream>>>(W1,   128, W1T_hi,   W1T_lo,   16384);
  wsplit<<<20, 256, 0, stream>>>(W2,    40, W2T_hi,   W2T_lo,    5120);
  catbias<<<1, 256, 0, stream>>>(bl, br, bcat);

  count_kernel<<<(E + 255)/256, 256, 0, stream>>>(ei, cursor, E);
  scan1_kernel<<<nb, 256, 0, stream>>>(cursor, rowptr, bsum, N);
  scan2_kernel<<<1, 512, 0, stream>>>(bsum, boff, nb);
  scan3_kernel<<<nb, 256, 0, stream>>>(rowptr, boff, N);
  hipMemcpyAsync(cursor, rowptr, (size_t)N * sizeof(int), hipMemcpyDeviceToDevice, stream);
  fill_kernel<<<(E + 255)/256, 256, 0, stream>>>(ei, ew, cursor, erec, E);

  const int gg = (N + 63) / 64;
  mgemm<false,false><<<gg, 256, 0, stream>>>(x, WpreT_hi, WpreT_lo, nullptr, hout, N, 128);
  mgemm512<<<gg, 512, 0, stream>>>(hout, WlrT_hi, WlrT_lo, bcat, xlr, N);

  gather_kernel<<<(N + 3)/4, 256, 0, stream>>>(rowptr, erec, xlr, We, att, msum, bgat, hout, N);

  mgemm<true, true ><<<gg, 256, 0, stream>>>(hout, W1T_hi, W1T_lo, b1, tbuf,   N, 128);
  mgemm<true, false><<<gg, 256, 0, stream>>>(tbuf, W2T_hi, W2T_lo, b2, logits, N, 40);
}

// Round 5
// 463.103 us; speedup vs baseline: 4.0733x; 1.1287x over previous
//
#include <hip/hip_runtime.h>

typedef __attribute__((ext_vector_type(8))) short short8;
typedef __attribute__((ext_vector_type(16))) float f32x16;

#if __has_builtin(__builtin_amdgcn_exp2f)
#define EXP2(x) __builtin_amdgcn_exp2f(x)
#else
#define EXP2(x) exp2f(x)
#endif

static __device__ __forceinline__ unsigned short f2bf(float f){
  unsigned u = __float_as_uint(f);
  unsigned r = u + 0x7fffu + ((u >> 16) & 1u);
  return (unsigned short)(r >> 16);
}
static __device__ __forceinline__ float bf2f(unsigned short h){
  return __uint_as_float(((unsigned)h) << 16);
}

// ---------------- mean of edge weights ----------------
__global__ void mean_kernel(const float* __restrict__ ew, float* __restrict__ msum, int E){
  float s = 0.f;
  for (int i = blockIdx.x*blockDim.x + threadIdx.x; i < E; i += gridDim.x*blockDim.x) s += ew[i];
  for (int d = 32; d > 0; d >>= 1) s += __shfl_down(s, d, 64);
  __shared__ float ps[4];
  int lane = threadIdx.x & 63, w = threadIdx.x >> 6;
  if (lane == 0) ps[w] = s;
  __syncthreads();
  if (threadIdx.x == 0){
    float tot = ps[0] + ps[1] + ps[2] + ps[3];
    atomicAdd(msum, tot / (float)E);
  }
}

// ---------------- weight transpose + hi/lo bf16 split ----------------
__global__ void wsplit(const float* __restrict__ W, int ncol,
                       unsigned short* __restrict__ hi, unsigned short* __restrict__ lo, int nelem){
  int i = blockIdx.x*256 + threadIdx.x;
  if (i >= nelem) return;
  int c = i >> 7, k = i & 127;
  float v = W[(size_t)k*ncol + c];
  unsigned short h = f2bf(v);
  hi[i] = h;
  lo[i] = f2bf(v - bf2f(h));
}

__global__ void wsplit_lr(const float* __restrict__ Wl, const float* __restrict__ Wr,
                          unsigned short* __restrict__ hi, unsigned short* __restrict__ lo){
  int i = blockIdx.x*256 + threadIdx.x;   // 256*128 elems
  if (i >= 256*128) return;
  int c = i >> 7, k = i & 127;
  float v = (c < 128) ? Wl[(size_t)k*128 + c] : Wr[(size_t)k*128 + (c-128)];
  unsigned short h = f2bf(v);
  hi[i] = h;
  lo[i] = f2bf(v - bf2f(h));
}

__global__ void catbias(const float* __restrict__ bl, const float* __restrict__ br,
                        float* __restrict__ o){
  int i = threadIdx.x;
  o[i] = (i < 128) ? bl[i] : br[i-128];
}

// ---------------- CSR build ----------------
__global__ void count_kernel(const int* __restrict__ ei, int* __restrict__ deg, int E){
  int e = blockIdx.x*256 + threadIdx.x;
  if (e < E) atomicAdd(&deg[ei[E + e]], 1);
}

__global__ __launch_bounds__(256) void scan1_kernel(const int* __restrict__ deg, int* __restrict__ rowptr,
                                                    int* __restrict__ bsum, int N){
  __shared__ int s[256];
  int i = blockIdx.x*256 + threadIdx.x;
  int v = (i < N) ? deg[i] : 0;
  s[threadIdx.x] = v;
  __syncthreads();
  for (int off = 1; off < 256; off <<= 1){
    int t = (threadIdx.x >= off) ? s[threadIdx.x - off] : 0;
    __syncthreads();
    s[threadIdx.x] += t;
    __syncthreads();
  }
  if (i < N) rowptr[i + 1] = s[threadIdx.x];
  if (threadIdx.x == 255) bsum[blockIdx.x] = s[255];
}

__global__ __launch_bounds__(512) void scan2_kernel(const int* __restrict__ bsum, int* __restrict__ boff, int nb){
  __shared__ int s[512];
  int v = (threadIdx.x < nb) ? bsum[threadIdx.x] : 0;
  s[threadIdx.x] = v;
  __syncthreads();
  for (int off = 1; off < 512; off <<= 1){
    int t = (threadIdx.x >= off) ? s[threadIdx.x - off] : 0;
    __syncthreads();
    s[threadIdx.x] += t;
    __syncthreads();
  }
  if (threadIdx.x < nb) boff[threadIdx.x] = s[threadIdx.x] - v;
}

__global__ void scan3_kernel(int* __restrict__ rowptr, const int* __restrict__ boff, int N){
  int i = blockIdx.x*256 + threadIdx.x;
  if (i == 0) rowptr[0] = 0;
  if (i < N) rowptr[i + 1] += boff[i >> 8];
}

__global__ void fill_kernel(const int* __restrict__ ei, const float* __restrict__ ew,
                            int* __restrict__ cursor, int2* __restrict__ erec, int E){
  int e = blockIdx.x*256 + threadIdx.x;
  if (e >= E) return;
  int dst = ei[E + e];
  int pos = atomicAdd(&cursor[dst], 1);
  erec[pos] = make_int2(ei[e], __float_as_int(ew[e]));
}

// ---------------- shared device helper: stage A tile (64x128 fp32 -> split bf16 LDS) ----------------
template<int NT>
static __device__ __forceinline__ void stageA(short* alds, const float* __restrict__ A,
                                              int row0, int N, int t){
  for (int g = t; g < 1024; g += NT){
    int r = g >> 4, k8 = g & 15;
    int grow = row0 + r;
    float4 p0, p1;
    if (grow < N){
      const float* ap = A + (size_t)grow*128 + k8*8;
      p0 = *(const float4*)ap;
      p1 = *(const float4*)(ap + 4);
    } else {
      p0 = make_float4(0.f,0.f,0.f,0.f); p1 = p0;
    }
    float vv[8] = {p0.x,p0.y,p0.z,p0.w,p1.x,p1.y,p1.z,p1.w};
    short8 hv, lv;
    #pragma unroll
    for (int j = 0; j < 8; ++j){
      unsigned short h = f2bf(vv[j]);
      hv[j] = (short)h;
      lv[j] = (short)f2bf(vv[j] - bf2f(h));
    }
    int slot = k8 ^ (r & 15);
    *(short8*)&alds[r*128 + slot*8] = hv;
    *(short8*)&alds[8192 + r*128 + slot*8] = lv;
  }
}

// 3-pass MFMA over one 32-row block pair, A from LDS, B frags in regs
#define MFMA_KLOOP(ACC0, ACC1) \
  _Pragma("unroll") \
  for (int ks = 0; ks < 8; ++ks){ \
    int k8 = ks*2 + kg; \
    const short* a0 = &alds[r0*128 + (k8 ^ sx)*8]; \
    const short* a1 = &alds[(r0+32)*128 + (k8 ^ sx)*8]; \
    short8 a0h = *(const short8*)a0; \
    short8 a0l = *(const short8*)(a0 + 8192); \
    short8 a1h = *(const short8*)a1; \
    short8 a1l = *(const short8*)(a1 + 8192); \
    ACC0 = __builtin_amdgcn_mfma_f32_32x32x16_bf16(a0h, bh[ks],  ACC0, 0,0,0); \
    ACC1 = __builtin_amdgcn_mfma_f32_32x32x16_bf16(a1h, bh[ks],  ACC1, 0,0,0); \
    ACC0 = __builtin_amdgcn_mfma_f32_32x32x16_bf16(a0l, bh[ks],  ACC0, 0,0,0); \
    ACC1 = __builtin_amdgcn_mfma_f32_32x32x16_bf16(a1l, bh[ks],  ACC1, 0,0,0); \
    ACC0 = __builtin_amdgcn_mfma_f32_32x32x16_bf16(a0h, bl8[ks], ACC0, 0,0,0); \
    ACC1 = __builtin_amdgcn_mfma_f32_32x32x16_bf16(a1h, bl8[ks], ACC1, 0,0,0); \
  }

// ---------------- MFMA GEMM (4-wave, 128 cols, fp32 out) ----------------
template<bool BIAS>
__global__ __launch_bounds__(256) void mgemm(
    const float* __restrict__ A,
    const unsigned short* __restrict__ Bhi, const unsigned short* __restrict__ Blo,
    const float* __restrict__ bias, float* __restrict__ out, int N)
{
  __shared__ short alds[2*64*128];
  const int t = threadIdx.x;
  const int row0 = blockIdx.x * 64;
  stageA<256>(alds, A, row0, N, t);
  __syncthreads();

  const int lane = t & 63, w = t >> 6;
  const int cl = lane & 31, kg = lane >> 5;
  const int col = w*32 + cl;

  short8 bh[8], bl8[8];
  #pragma unroll
  for (int ks = 0; ks < 8; ++ks){
    size_t off = (size_t)col*128 + ks*16 + kg*8;
    bh[ks]  = *(const short8*)(Bhi + off);
    bl8[ks] = *(const short8*)(Blo + off);
  }

  f32x16 acc0, acc1;
  #pragma unroll
  for (int i = 0; i < 16; ++i){ acc0[i] = 0.f; acc1[i] = 0.f; }
  const int r0 = cl;
  const int sx = r0 & 15;
  MFMA_KLOOP(acc0, acc1)

  float bv = BIAS ? bias[col] : 0.f;
  #pragma unroll
  for (int rt = 0; rt < 2; ++rt){
    const f32x16& ac = rt ? acc1 : acc0;
    #pragma unroll
    for (int reg = 0; reg < 16; ++reg){
      int row = rt*32 + (reg & 3) + 8*(reg >> 2) + 4*kg;
      int grow = row0 + row;
      if (grow < N) out[(size_t)grow*128 + col] = ac[reg] + bv;
    }
  }
}

// ---------------- MFMA GEMM (8-wave, 256 cols, bf16 out): xlr = hout @ [Wl|Wr] + [bl|br] ----------------
__global__ __launch_bounds__(512) void mgemm512b(
    const float* __restrict__ A,
    const unsigned short* __restrict__ Bhi, const unsigned short* __restrict__ Blo,
    const float* __restrict__ bias, unsigned short* __restrict__ out, int N)
{
  __shared__ short alds[2*64*128];
  const int t = threadIdx.x;
  const int row0 = blockIdx.x * 64;
  stageA<512>(alds, A, row0, N, t);
  __syncthreads();

  const int lane = t & 63, w = t >> 6;
  const int cl = lane & 31, kg = lane >> 5;
  const int col = w*32 + cl;

  short8 bh[8], bl8[8];
  #pragma unroll
  for (int ks = 0; ks < 8; ++ks){
    size_t off = (size_t)col*128 + ks*16 + kg*8;
    bh[ks]  = *(const short8*)(Bhi + off);
    bl8[ks] = *(const short8*)(Blo + off);
  }

  f32x16 acc0, acc1;
  #pragma unroll
  for (int i = 0; i < 16; ++i){ acc0[i] = 0.f; acc1[i] = 0.f; }
  const int r0 = cl;
  const int sx = r0 & 15;
  MFMA_KLOOP(acc0, acc1)

  float bv = bias[col];
  #pragma unroll
  for (int rt = 0; rt < 2; ++rt){
    const f32x16& ac = rt ? acc1 : acc0;
    #pragma unroll
    for (int reg = 0; reg < 16; ++reg){
      int row = rt*32 + (reg & 3) + 8*(reg >> 2) + 4*kg;
      int grow = row0 + row;
      if (grow < N) out[(size_t)grow*256 + col] = f2bf(ac[reg] + bv);
    }
  }
}

// ---------------- fused MLP: logits = relu(h@W1+b1)@W2 + b2 ----------------
__global__ __launch_bounds__(256) void mlp_kernel(
    const float* __restrict__ A,
    const unsigned short* __restrict__ B1hi, const unsigned short* __restrict__ B1lo,
    const float* __restrict__ b1,
    const unsigned short* __restrict__ B2hi, const unsigned short* __restrict__ B2lo,
    const float* __restrict__ b2,
    float* __restrict__ logits, int N)
{
  __shared__ short alds[2*64*128];
  const int t = threadIdx.x;
  const int row0 = blockIdx.x * 64;
  stageA<256>(alds, A, row0, N, t);
  __syncthreads();

  const int lane = t & 63, w = t >> 6;
  const int cl = lane & 31, kg = lane >> 5;
  const int r0 = cl;
  const int sx = r0 & 15;

  // ---- phase 1: relu(h@W1 + b1), 4 waves x 32 cols ----
  {
    const int col = w*32 + cl;
    short8 bh[8], bl8[8];
    #pragma unroll
    for (int ks = 0; ks < 8; ++ks){
      size_t off = (size_t)col*128 + ks*16 + kg*8;
      bh[ks]  = *(const short8*)(B1hi + off);
      bl8[ks] = *(const short8*)(B1lo + off);
    }
    f32x16 acc0, acc1;
    #pragma unroll
    for (int i = 0; i < 16; ++i){ acc0[i] = 0.f; acc1[i] = 0.f; }
    MFMA_KLOOP(acc0, acc1)

    float bv = b1[col];
    __syncthreads();   // everyone done reading alds; safe to overwrite
    #pragma unroll
    for (int rt = 0; rt < 2; ++rt){
      const f32x16& ac = rt ? acc1 : acc0;
      #pragma unroll
      for (int reg = 0; reg < 16; ++reg){
        int row = rt*32 + (reg & 3) + 8*(reg >> 2) + 4*kg;
        float v = fmaxf(ac[reg] + bv, 0.f);
        unsigned short h = f2bf(v);
        unsigned short l = f2bf(v - bf2f(h));
        int idx = row*128 + (((col >> 3) ^ (row & 15)) << 3) + (col & 7);
        alds[idx] = (short)h;
        alds[8192 + idx] = (short)l;
      }
    }
    __syncthreads();
  }

  // ---- phase 2: logits = relu@W2 + b2, 40 cols (waves 0,1) ----
  if (w < 2){
    const int col = w*32 + cl;
    const bool cok = col < 40;
    short8 bh[8], bl8[8];
    #pragma unroll
    for (int ks = 0; ks < 8; ++ks){
      if (cok){
        size_t off = (size_t)col*128 + ks*16 + kg*8;
        bh[ks]  = *(const short8*)(B2hi + off);
        bl8[ks] = *(const short8*)(B2lo + off);
      } else {
        #pragma unroll
        for (int j = 0; j < 8; ++j){ bh[ks][j] = 0; bl8[ks][j] = 0; }
      }
    }
    f32x16 acc0, acc1;
    #pragma unroll
    for (int i = 0; i < 16; ++i){ acc0[i] = 0.f; acc1[i] = 0.f; }
    MFMA_KLOOP(acc0, acc1)

    if (cok){
      float bv = b2[col];
      #pragma unroll
      for (int rt = 0; rt < 2; ++rt){
        const f32x16& ac = rt ? acc1 : acc0;
        #pragma unroll
        for (int reg = 0; reg < 16; ++reg){
          int row = rt*32 + (reg & 3) + 8*(reg >> 2) + 4*kg;
          int grow = row0 + row;
          if (grow < N) logits[(size_t)grow*40 + col] = ac[reg] + bv;
        }
      }
    }
  }
}

// ---------------- gather: 4 edges/wave x 16 lanes/edge, bf16 xlr, fused epilogue ----------------
__global__ __launch_bounds__(256) void gather_kernel(
    const int* __restrict__ rowptr, const int2* __restrict__ erec,
    const unsigned short* __restrict__ xlr,     // [N][256] bf16: xl | xr
    const float* __restrict__ We, const float* __restrict__ att,
    const float* __restrict__ msum, const float* __restrict__ bgat,
    float* __restrict__ hbuf, int N)
{
  const int wid  = threadIdx.x >> 6;
  const int lane = threadIdx.x & 63;
  const int n = blockIdx.x * 4 + wid;
  if (n >= N) return;

  const int g   = lane >> 4;      // edge slot 0..3
  const int l   = lane & 15;      // channel sub-lane: channels [l*8, l*8+8)
  const int ch0 = l * 8;

  float xrv[8], wev[8], at6[8], at4[8];
  {
    short8 q = *(const short8*)&xlr[(size_t)n*256 + 128 + ch0];
    float4 w0 = *(const float4*)&We[ch0];
    float4 w1 = *(const float4*)&We[ch0+4];
    float4 a0 = *(const float4*)&att[ch0];
    float4 a1 = *(const float4*)&att[ch0+4];
    const float L2E = 1.4426950408889634f;
    float wv[8] = {w0.x,w0.y,w0.z,w0.w,w1.x,w1.y,w1.z,w1.w};
    float av[8] = {a0.x,a0.y,a0.z,a0.w,a1.x,a1.y,a1.z,a1.w};
    #pragma unroll
    for (int j = 0; j < 8; ++j){
      xrv[j] = bf2f((unsigned short)q[j]);
      wev[j] = wv[j];
      at6[j] = av[j]*0.6f*L2E;    // lrelu(z) = 0.6z + 0.4|z|, fold log2(e)
      at4[j] = av[j]*0.4f*L2E;
    }
  }

  float num[8];
  #pragma unroll
  for (int j = 0; j < 8; ++j) num[j] = 0.f;
  float den = 0.f;

  const int beg = rowptr[n], end = rowptr[n + 1];
  const float wm = msum[0];

  for (int base = beg; base <= end; base += 4){
    int i = base + g;
    int src = n; float w = wm;
    if (i < end){ int2 r = erec[i]; src = r.x; w = __int_as_float(r.y); }
    const bool act = (i <= end);

    short8 pv = *(const short8*)&xlr[(size_t)src*256 + ch0];
    float xlv[8];
    #pragma unroll
    for (int j = 0; j < 8; ++j) xlv[j] = bf2f((unsigned short)pv[j]);

    float p = 0.f;
    #pragma unroll
    for (int j = 0; j < 8; ++j){
      float z = fmaf(w, wev[j], xlv[j] + xrv[j]);
      p = fmaf(at6[j], z, p);
      p = fmaf(at4[j], fabsf(z), p);
    }
    p += __shfl_xor(p, 1, 64);
    p += __shfl_xor(p, 2, 64);
    float ex = act ? EXP2(p) : 0.f;
    den += ex;
    #pragma unroll
    for (int j = 0; j < 8; ++j) num[j] = fmaf(ex, xlv[j], num[j]);
  }

  #pragma unroll
  for (int j = 0; j < 8; ++j){
    num[j] += __shfl_xor(num[j], 16, 64);
    num[j] += __shfl_xor(num[j], 32, 64);
  }
  den += __shfl_xor(den, 16, 64);
  den += __shfl_xor(den, 32, 64);

  if (g == 0){
    float inv = 1.f / (den + 1e-16f);
    float o[8];
    #pragma unroll
    for (int j = 0; j < 8; ++j){
      float v = num[j]*inv + bgat[ch0+j];
      o[j] = v > 0.f ? v : expm1f(v);   // ELU
    }
    float4 h0a = *(const float4*)&hbuf[(size_t)n*128 + ch0];
    float4 h0b = *(const float4*)&hbuf[(size_t)n*128 + ch0 + 4];
    h0a.x += o[0]; h0a.y += o[1]; h0a.z += o[2]; h0a.w += o[3];
    h0b.x += o[4]; h0b.y += o[5]; h0b.z += o[6]; h0b.w += o[7];
    *(float4*)&hbuf[(size_t)n*128 + ch0]     = h0a;
    *(float4*)&hbuf[(size_t)n*128 + ch0 + 4] = h0b;
  }
}

extern "C" void kernel_launch(void* const* d_in, const int* in_sizes, int n_in,
                              void* d_out, int out_size, void* d_ws, size_t ws_size,
                              hipStream_t stream)
{
  const float* x    = (const float*)d_in[0];
  const int*   ei   = (const int*)  d_in[1];
  const float* ew   = (const float*)d_in[2];
  const float* Wpre = (const float*)d_in[3];
  const float* Wl   = (const float*)d_in[4];
  const float* bl   = (const float*)d_in[5];
  const float* Wr   = (const float*)d_in[6];
  const float* br   = (const float*)d_in[7];
  const float* We   = (const float*)d_in[8];
  const float* att  = (const float*)d_in[9];
  const float* bgat = (const float*)d_in[10];
  const float* W1   = (const float*)d_in[11];
  const float* b1   = (const float*)d_in[12];
  const float* W2   = (const float*)d_in[13];
  const float* b2   = (const float*)d_in[14];

  const int N = in_sizes[0] / 128;
  const int E = in_sizes[2];
  const int nb = (N + 255) / 256;

  float* hout   = (float*)d_out;               // [N,128]
  float* logits = hout + (size_t)N*128;        // [N,40]

  // workspace layout
  unsigned short* xlr = (unsigned short*)d_ws; // N*256 bf16 (xl | xr per row)
  int2*  erec   = (int2*)(xlr + (size_t)N*256);// E records (src, w)
  int*   rowptr = (int*)(erec + E);            // N+1
  int*   cursor = rowptr + N + 1;              // N (doubles as deg)
  float* msum   = (float*)(cursor + N);        // 1
  int*   bsum   = (int*)(msum + 1);            // nb
  int*   boff   = bsum + nb;                   // nb
  float* bcat   = (float*)(boff + nb);         // 256
  unsigned short* wsp = (unsigned short*)(((uintptr_t)(bcat + 256) + 15) & ~(uintptr_t)15);
  unsigned short* WpreT_hi = wsp;              // 128*128
  unsigned short* WpreT_lo = WpreT_hi + 16384;
  unsigned short* WlrT_hi  = WpreT_lo + 16384; // 256*128
  unsigned short* WlrT_lo  = WlrT_hi  + 32768;
  unsigned short* W1T_hi   = WlrT_lo  + 32768; // 128*128
  unsigned short* W1T_lo   = W1T_hi   + 16384;
  unsigned short* W2T_hi   = W1T_lo   + 16384; // 40*128
  unsigned short* W2T_lo   = W2T_hi   + 5120;

  hipMemsetAsync(cursor, 0, (size_t)(N + 1) * sizeof(int), stream);

  mean_kernel<<<256, 256, 0, stream>>>(ew, msum, E);

  wsplit<<<64, 256, 0, stream>>>(Wpre, 128, WpreT_hi, WpreT_lo, 16384);
  wsplit_lr<<<128, 256, 0, stream>>>(Wl, Wr, WlrT_hi, WlrT_lo);
  wsplit<<<64, 256, 0, stream>>>(W1,   128, W1T_hi,   W1T_lo,   16384);
  wsplit<<<20, 256, 0, stream>>>(W2,    40, W2T_hi,   W2T_lo,    5120);
  catbias<<<1, 256, 0, stream>>>(bl, br, bcat);

  count_kernel<<<(E + 255)/256, 256, 0, stream>>>(ei, cursor, E);
  scan1_kernel<<<nb, 256, 0, stream>>>(cursor, rowptr, bsum, N);
  scan2_kernel<<<1, 512, 0, stream>>>(bsum, boff, nb);
  scan3_kernel<<<nb, 256, 0, stream>>>(rowptr, boff, N);
  hipMemcpyAsync(cursor, rowptr, (size_t)N * sizeof(int), hipMemcpyDeviceToDevice, stream);
  fill_kernel<<<(E + 255)/256, 256, 0, stream>>>(ei, ew, cursor, erec, E);

  const int gg = (N + 63) / 64;
  mgemm<false><<<gg, 256, 0, stream>>>(x, WpreT_hi, WpreT_lo, nullptr, hout, N);
  mgemm512b<<<gg, 512, 0, stream>>>(hout, WlrT_hi, WlrT_lo, bcat, xlr, N);

  gather_kernel<<<(N + 3)/4, 256, 0, stream>>>(rowptr, erec, xlr, We, att, msum, bgat, hout, N);

  mlp_kernel<<<gg, 256, 0, stream>>>(hout, W1T_hi, W1T_lo, b1, W2T_hi, W2T_lo, b2, logits, N);
}

// Round 6
// 454.003 us; speedup vs baseline: 4.1549x; 1.0200x over previous
//
#include <hip/hip_runtime.h>

typedef __attribute__((ext_vector_type(8))) short short8;
typedef __attribute__((ext_vector_type(16))) float f32x16;

#if __has_builtin(__builtin_amdgcn_exp2f)
#define EXP2(x) __builtin_amdgcn_exp2f(x)
#else
#define EXP2(x) exp2f(x)
#endif

static __device__ __forceinline__ unsigned short f2bf(float f){
  unsigned u = __float_as_uint(f);
  unsigned r = u + 0x7fffu + ((u >> 16) & 1u);
  return (unsigned short)(r >> 16);
}
static __device__ __forceinline__ float bf2f(unsigned short h){
  return __uint_as_float(((unsigned)h) << 16);
}

// ---------------- all weight prep in one kernel ----------------
__global__ void wprep(const float* __restrict__ Wpre, const float* __restrict__ Wl,
                      const float* __restrict__ Wr, const float* __restrict__ W1,
                      const float* __restrict__ W2, const float* __restrict__ bl,
                      const float* __restrict__ br,
                      unsigned short* __restrict__ Phi, unsigned short* __restrict__ Plo,
                      unsigned short* __restrict__ Lhi, unsigned short* __restrict__ Llo,
                      unsigned short* __restrict__ W1hi, unsigned short* __restrict__ W1lo,
                      unsigned short* __restrict__ W2hi, unsigned short* __restrict__ W2lo,
                      float* __restrict__ bcat){
  int i = blockIdx.x*256 + threadIdx.x;
  float v; unsigned short* hp; unsigned short* lp; int oi;
  if (i < 16384){
    int c = i >> 7, k = i & 127;
    v = Wpre[(size_t)k*128 + c]; hp = Phi; lp = Plo; oi = i;
  } else if (i < 49152){
    int j = i - 16384; int c = j >> 7, k = j & 127;
    v = (c < 128) ? Wl[(size_t)k*128 + c] : Wr[(size_t)k*128 + (c-128)];
    hp = Lhi; lp = Llo; oi = j;
  } else if (i < 65536){
    int j = i - 49152; int c = j >> 7, k = j & 127;
    v = W1[(size_t)k*128 + c]; hp = W1hi; lp = W1lo; oi = j;
  } else if (i < 70656){
    int j = i - 65536; int c = j >> 7, k = j & 127;
    v = W2[(size_t)k*40 + c]; hp = W2hi; lp = W2lo; oi = j;
  } else if (i < 70912){
    int j = i - 70656;
    bcat[j] = (j < 128) ? bl[j] : br[j-128];
    return;
  } else return;
  unsigned short h = f2bf(v);
  hp[oi] = h;
  lp[oi] = f2bf(v - bf2f(h));
}

// ---------------- histogram + mean in one pass ----------------
__global__ void count_mean(const int* __restrict__ ei, const float* __restrict__ ew,
                           int* __restrict__ deg, float* __restrict__ msum, int E){
  float s = 0.f;
  for (int e = blockIdx.x*256 + threadIdx.x; e < E; e += gridDim.x*256){
    atomicAdd(&deg[ei[E + e]], 1);
    s += ew[e];
  }
  for (int d = 32; d > 0; d >>= 1) s += __shfl_down(s, d, 64);
  __shared__ float ps[4];
  int lane = threadIdx.x & 63, w = threadIdx.x >> 6;
  if (lane == 0) ps[w] = s;
  __syncthreads();
  if (threadIdx.x == 0) atomicAdd(msum, (ps[0]+ps[1]+ps[2]+ps[3]) / (float)E);
}

// ---------------- scans ----------------
__global__ __launch_bounds__(256) void scan1_kernel(const int* __restrict__ deg, int* __restrict__ rowptr,
                                                    int* __restrict__ bsum, int N){
  __shared__ int s[256];
  int i = blockIdx.x*256 + threadIdx.x;
  int v = (i < N) ? deg[i] : 0;
  s[threadIdx.x] = v;
  __syncthreads();
  for (int off = 1; off < 256; off <<= 1){
    int t = (threadIdx.x >= off) ? s[threadIdx.x - off] : 0;
    __syncthreads();
    s[threadIdx.x] += t;
    __syncthreads();
  }
  if (i < N) rowptr[i + 1] = s[threadIdx.x];
  if (threadIdx.x == 255) bsum[blockIdx.x] = s[255];
}

__global__ __launch_bounds__(512) void scan2_kernel(const int* __restrict__ bsum, int* __restrict__ boff, int nb){
  __shared__ int s[512];
  int v = (threadIdx.x < nb) ? bsum[threadIdx.x] : 0;
  s[threadIdx.x] = v;
  __syncthreads();
  for (int off = 1; off < 512; off <<= 1){
    int t = (threadIdx.x >= off) ? s[threadIdx.x - off] : 0;
    __syncthreads();
    s[threadIdx.x] += t;
    __syncthreads();
  }
  if (threadIdx.x < nb) boff[threadIdx.x] = s[threadIdx.x] - v;
}

__global__ void scan3_kernel(int* __restrict__ rowptr, const int* __restrict__ boff, int N){
  int i = blockIdx.x*256 + threadIdx.x;
  if (i == 0) rowptr[0] = 0;
  if (i < N) rowptr[i + 1] += boff[i >> 8];
}

__global__ void fill_kernel(const int* __restrict__ ei, const float* __restrict__ ew,
                            int* __restrict__ cursor, int2* __restrict__ erec, int E){
  int e = blockIdx.x*256 + threadIdx.x;
  if (e >= E) return;
  int dst = ei[E + e];
  int pos = atomicAdd(&cursor[dst], 1);
  erec[pos] = make_int2(ei[e], __float_as_int(ew[e]));
}

// ---------------- stage A tile (64x128 fp32 -> split bf16 LDS) ----------------
template<int NT>
static __device__ __forceinline__ void stageA(short* alds, const float* __restrict__ A,
                                              int row0, int N, int t){
  for (int g = t; g < 1024; g += NT){
    int r = g >> 4, k8 = g & 15;
    int grow = row0 + r;
    float4 p0, p1;
    if (grow < N){
      const float* ap = A + (size_t)grow*128 + k8*8;
      p0 = *(const float4*)ap;
      p1 = *(const float4*)(ap + 4);
    } else {
      p0 = make_float4(0.f,0.f,0.f,0.f); p1 = p0;
    }
    float vv[8] = {p0.x,p0.y,p0.z,p0.w,p1.x,p1.y,p1.z,p1.w};
    short8 hv, lv;
    #pragma unroll
    for (int j = 0; j < 8; ++j){
      unsigned short h = f2bf(vv[j]);
      hv[j] = (short)h;
      lv[j] = (short)f2bf(vv[j] - bf2f(h));
    }
    int slot = k8 ^ (r & 15);
    *(short8*)&alds[r*128 + slot*8] = hv;
    *(short8*)&alds[8192 + r*128 + slot*8] = lv;
  }
}

// 3-pass MFMA over two 32-row tiles, A from LDS, B frags in regs
#define MFMA_KLOOP(ACC0, ACC1) \
  _Pragma("unroll") \
  for (int ks = 0; ks < 8; ++ks){ \
    int k8 = ks*2 + kg; \
    const short* a0 = &alds[r0*128 + (k8 ^ sx)*8]; \
    const short* a1 = &alds[(r0+32)*128 + (k8 ^ sx)*8]; \
    short8 a0h = *(const short8*)a0; \
    short8 a0l = *(const short8*)(a0 + 8192); \
    short8 a1h = *(const short8*)a1; \
    short8 a1l = *(const short8*)(a1 + 8192); \
    ACC0 = __builtin_amdgcn_mfma_f32_32x32x16_bf16(a0h, bh[ks],  ACC0, 0,0,0); \
    ACC1 = __builtin_amdgcn_mfma_f32_32x32x16_bf16(a1h, bh[ks],  ACC1, 0,0,0); \
    ACC0 = __builtin_amdgcn_mfma_f32_32x32x16_bf16(a0l, bh[ks],  ACC0, 0,0,0); \
    ACC1 = __builtin_amdgcn_mfma_f32_32x32x16_bf16(a1l, bh[ks],  ACC1, 0,0,0); \
    ACC0 = __builtin_amdgcn_mfma_f32_32x32x16_bf16(a0h, bl8[ks], ACC0, 0,0,0); \
    ACC1 = __builtin_amdgcn_mfma_f32_32x32x16_bf16(a1h, bl8[ks], ACC1, 0,0,0); \
  }

// ---------------- fused pre: hout = x@Wpre (fp32) ; xlr = h0@[Wl|Wr]+bcat (bf16) ----------------
__global__ __launch_bounds__(512) void pre_kernel(
    const float* __restrict__ A,
    const unsigned short* __restrict__ Phi, const unsigned short* __restrict__ Plo,
    const unsigned short* __restrict__ Lhi, const unsigned short* __restrict__ Llo,
    const float* __restrict__ bcat,
    float* __restrict__ hout, unsigned short* __restrict__ xlr, int N)
{
  __shared__ short alds[2*64*128];
  const int t = threadIdx.x;
  const int row0 = blockIdx.x * 64;
  stageA<512>(alds, A, row0, N, t);
  __syncthreads();

  const int lane = t & 63, w = t >> 6;
  const int cl = lane & 31, kg = lane >> 5;
  const int sx = cl & 15;

  // ---- phase 1: h0 = x@Wpre; wave w -> row-tile rt=w&1, col-tile ct=w>>1 ----
  {
    const int rt = w & 1, ct = w >> 1;
    const int colp = ct*32 + cl;
    short8 bh[8], bl8[8];
    #pragma unroll
    for (int ks = 0; ks < 8; ++ks){
      size_t off = (size_t)colp*128 + ks*16 + kg*8;
      bh[ks]  = *(const short8*)(Phi + off);
      bl8[ks] = *(const short8*)(Plo + off);
    }
    f32x16 acc;
    #pragma unroll
    for (int i = 0; i < 16; ++i) acc[i] = 0.f;
    const int r0 = rt*32 + cl;
    #pragma unroll
    for (int ks = 0; ks < 8; ++ks){
      int k8 = ks*2 + kg;
      const short* a = &alds[r0*128 + (k8 ^ sx)*8];
      short8 ah = *(const short8*)a;
      short8 al = *(const short8*)(a + 8192);
      acc = __builtin_amdgcn_mfma_f32_32x32x16_bf16(ah, bh[ks],  acc, 0,0,0);
      acc = __builtin_amdgcn_mfma_f32_32x32x16_bf16(al, bh[ks],  acc, 0,0,0);
      acc = __builtin_amdgcn_mfma_f32_32x32x16_bf16(ah, bl8[ks], acc, 0,0,0);
    }
    __syncthreads();   // all x-tile reads done; safe to overwrite alds
    #pragma unroll
    for (int reg = 0; reg < 16; ++reg){
      int row = rt*32 + (reg & 3) + 8*(reg >> 2) + 4*kg;
      float v = acc[reg];
      int grow = row0 + row;
      if (grow < N) hout[(size_t)grow*128 + colp] = v;
      unsigned short h = f2bf(v);
      unsigned short l = f2bf(v - bf2f(h));
      int idx = row*128 + (((colp >> 3) ^ (row & 15)) << 3) + (colp & 7);
      alds[idx] = (short)h;
      alds[8192 + idx] = (short)l;
    }
  }
  __syncthreads();

  // ---- phase 2: xlr = h0 @ [Wl|Wr] + bcat; wave w -> cols w*32.. ----
  {
    const int col = w*32 + cl;
    short8 bh[8], bl8[8];
    #pragma unroll
    for (int ks = 0; ks < 8; ++ks){
      size_t off = (size_t)col*128 + ks*16 + kg*8;
      bh[ks]  = *(const short8*)(Lhi + off);
      bl8[ks] = *(const short8*)(Llo + off);
    }
    f32x16 acc0, acc1;
    #pragma unroll
    for (int i = 0; i < 16; ++i){ acc0[i] = 0.f; acc1[i] = 0.f; }
    const int r0 = cl;
    MFMA_KLOOP(acc0, acc1)
    float bv = bcat[col];
    #pragma unroll
    for (int rt2 = 0; rt2 < 2; ++rt2){
      const f32x16& ac = rt2 ? acc1 : acc0;
      #pragma unroll
      for (int reg = 0; reg < 16; ++reg){
        int row = rt2*32 + (reg & 3) + 8*(reg >> 2) + 4*kg;
        int grow = row0 + row;
        if (grow < N) xlr[(size_t)grow*256 + col] = f2bf(ac[reg] + bv);
      }
    }
  }
}

// ---------------- fused MLP: logits = relu(h@W1+b1)@W2 + b2 ----------------
__global__ __launch_bounds__(256) void mlp_kernel(
    const float* __restrict__ A,
    const unsigned short* __restrict__ B1hi, const unsigned short* __restrict__ B1lo,
    const float* __restrict__ b1,
    const unsigned short* __restrict__ B2hi, const unsigned short* __restrict__ B2lo,
    const float* __restrict__ b2,
    float* __restrict__ logits, int N)
{
  __shared__ short alds[2*64*128];
  const int t = threadIdx.x;
  const int row0 = blockIdx.x * 64;
  stageA<256>(alds, A, row0, N, t);
  __syncthreads();

  const int lane = t & 63, w = t >> 6;
  const int cl = lane & 31, kg = lane >> 5;
  const int r0 = cl;
  const int sx = r0 & 15;

  {
    const int col = w*32 + cl;
    short8 bh[8], bl8[8];
    #pragma unroll
    for (int ks = 0; ks < 8; ++ks){
      size_t off = (size_t)col*128 + ks*16 + kg*8;
      bh[ks]  = *(const short8*)(B1hi + off);
      bl8[ks] = *(const short8*)(B1lo + off);
    }
    f32x16 acc0, acc1;
    #pragma unroll
    for (int i = 0; i < 16; ++i){ acc0[i] = 0.f; acc1[i] = 0.f; }
    MFMA_KLOOP(acc0, acc1)

    float bv = b1[col];
    __syncthreads();
    #pragma unroll
    for (int rt = 0; rt < 2; ++rt){
      const f32x16& ac = rt ? acc1 : acc0;
      #pragma unroll
      for (int reg = 0; reg < 16; ++reg){
        int row = rt*32 + (reg & 3) + 8*(reg >> 2) + 4*kg;
        float v = fmaxf(ac[reg] + bv, 0.f);
        unsigned short h = f2bf(v);
        unsigned short l = f2bf(v - bf2f(h));
        int idx = row*128 + (((col >> 3) ^ (row & 15)) << 3) + (col & 7);
        alds[idx] = (short)h;
        alds[8192 + idx] = (short)l;
      }
    }
    __syncthreads();
  }

  if (w < 2){
    const int col = w*32 + cl;
    const bool cok = col < 40;
    short8 bh[8], bl8[8];
    #pragma unroll
    for (int ks = 0; ks < 8; ++ks){
      if (cok){
        size_t off = (size_t)col*128 + ks*16 + kg*8;
        bh[ks]  = *(const short8*)(B2hi + off);
        bl8[ks] = *(const short8*)(B2lo + off);
      } else {
        #pragma unroll
        for (int j = 0; j < 8; ++j){ bh[ks][j] = 0; bl8[ks][j] = 0; }
      }
    }
    f32x16 acc0, acc1;
    #pragma unroll
    for (int i = 0; i < 16; ++i){ acc0[i] = 0.f; acc1[i] = 0.f; }
    MFMA_KLOOP(acc0, acc1)

    if (cok){
      float bv = b2[col];
      #pragma unroll
      for (int rt = 0; rt < 2; ++rt){
        const f32x16& ac = rt ? acc1 : acc0;
        #pragma unroll
        for (int reg = 0; reg < 16; ++reg){
          int row = rt*32 + (reg & 3) + 8*(reg >> 2) + 4*kg;
          int grow = row0 + row;
          if (grow < N) logits[(size_t)grow*40 + col] = ac[reg] + bv;
        }
      }
    }
  }
}

// ---------------- gather: 4 edges/wave x 16 lanes/edge, coalesced record burst + depth-2 pipeline ----------------
__global__ __launch_bounds__(256) void gather_kernel(
    const int* __restrict__ rowptr, const int2* __restrict__ erec,
    const unsigned short* __restrict__ xlr,     // [N][256] bf16: xl | xr
    const float* __restrict__ We, const float* __restrict__ att,
    const float* __restrict__ msum, const float* __restrict__ bgat,
    float* __restrict__ hbuf, int N)
{
  const int wid  = threadIdx.x >> 6;
  const int lane = threadIdx.x & 63;
  const int n = blockIdx.x * 4 + wid;
  if (n >= N) return;

  const int g   = lane >> 4;      // edge slot 0..3
  const int l   = lane & 15;      // channels [l*8, l*8+8)
  const int ch0 = l * 8;

  float xrv[8], wev[8], at6[8], at4[8];
  {
    short8 q = *(const short8*)&xlr[(size_t)n*256 + 128 + ch0];
    float4 w0 = *(const float4*)&We[ch0];
    float4 w1 = *(const float4*)&We[ch0+4];
    float4 a0 = *(const float4*)&att[ch0];
    float4 a1 = *(const float4*)&att[ch0+4];
    const float L2E = 1.4426950408889634f;
    float wv[8] = {w0.x,w0.y,w0.z,w0.w,w1.x,w1.y,w1.z,w1.w};
    float av[8] = {a0.x,a0.y,a0.z,a0.w,a1.x,a1.y,a1.z,a1.w};
    #pragma unroll
    for (int j = 0; j < 8; ++j){
      xrv[j] = bf2f((unsigned short)q[j]);
      wev[j] = wv[j];
      at6[j] = av[j]*0.6f*L2E;    // lrelu(z) = 0.6z + 0.4|z|, fold log2(e)
      at4[j] = av[j]*0.4f*L2E;
    }
  }

  float num[8];
  #pragma unroll
  for (int j = 0; j < 8; ++j) num[j] = 0.f;
  float den = 0.f;

  const int beg = rowptr[n], end = rowptr[n + 1];
  const float wm = msum[0];

  for (int seg = beg; seg <= end; seg += 64){
    // coalesced burst: 64 records in one shot; lanes past end hold the self-loop
    int idx = seg + lane;
    int rs = n; float rw = wm;
    if (idx < end){ int2 rr = erec[idx]; rs = rr.x; rw = __int_as_float(rr.y); }
    const int rem = end - seg;                  // self-loop slot index if < 64
    const int m = (rem + 1 < 64) ? rem + 1 : 64;
    const int nIter = (m + 3) >> 2;

    // depth-2 pipeline on xl loads; record fetch via shfl (register-resident)
    int sA = __shfl(rs, g, 64);
    short8 pvA = *(const short8*)&xlr[(size_t)sA*256 + ch0];
    int sB = __shfl(rs, (4 + g) & 63, 64);
    short8 pvB = *(const short8*)&xlr[(size_t)sB*256 + ch0];

    for (int t = 0; t < nIter; ++t){
      int sC = __shfl(rs, ((t+2)*4 + g) & 63, 64);
      short8 pvC = *(const short8*)&xlr[(size_t)sC*256 + ch0];

      int j = t*4 + g;
      float wj = __shfl(rw, j, 64);
      bool act = (j <= rem);

      float xlv[8];
      #pragma unroll
      for (int q = 0; q < 8; ++q) xlv[q] = bf2f((unsigned short)pvA[q]);

      float p = 0.f;
      #pragma unroll
      for (int q = 0; q < 8; ++q){
        float z = fmaf(wj, wev[q], xlv[q] + xrv[q]);
        p = fmaf(at6[q], z, p);
        p = fmaf(at4[q], fabsf(z), p);
      }
      p += __shfl_xor(p, 1, 64);
      p += __shfl_xor(p, 2, 64);
      float ex = act ? EXP2(p) : 0.f;
      den += ex;
      #pragma unroll
      for (int q = 0; q < 8; ++q) num[q] = fmaf(ex, xlv[q], num[q]);

      pvA = pvB; pvB = pvC;
    }
  }

  #pragma unroll
  for (int j = 0; j < 8; ++j){
    num[j] += __shfl_xor(num[j], 16, 64);
    num[j] += __shfl_xor(num[j], 32, 64);
  }
  den += __shfl_xor(den, 16, 64);
  den += __shfl_xor(den, 32, 64);

  if (g == 0){
    float inv = 1.f / (den + 1e-16f);
    float o[8];
    #pragma unroll
    for (int j = 0; j < 8; ++j){
      float v = num[j]*inv + bgat[ch0+j];
      o[j] = v > 0.f ? v : expm1f(v);   // ELU
    }
    float4 h0a = *(const float4*)&hbuf[(size_t)n*128 + ch0];
    float4 h0b = *(const float4*)&hbuf[(size_t)n*128 + ch0 + 4];
    h0a.x += o[0]; h0a.y += o[1]; h0a.z += o[2]; h0a.w += o[3];
    h0b.x += o[4]; h0b.y += o[5]; h0b.z += o[6]; h0b.w += o[7];
    *(float4*)&hbuf[(size_t)n*128 + ch0]     = h0a;
    *(float4*)&hbuf[(size_t)n*128 + ch0 + 4] = h0b;
  }
}

extern "C" void kernel_launch(void* const* d_in, const int* in_sizes, int n_in,
                              void* d_out, int out_size, void* d_ws, size_t ws_size,
                              hipStream_t stream)
{
  const float* x    = (const float*)d_in[0];
  const int*   ei   = (const int*)  d_in[1];
  const float* ew   = (const float*)d_in[2];
  const float* Wpre = (const float*)d_in[3];
  const float* Wl   = (const float*)d_in[4];
  const float* bl   = (const float*)d_in[5];
  const float* Wr   = (const float*)d_in[6];
  const float* br   = (const float*)d_in[7];
  const float* We   = (const float*)d_in[8];
  const float* att  = (const float*)d_in[9];
  const float* bgat = (const float*)d_in[10];
  const float* W1   = (const float*)d_in[11];
  const float* b1   = (const float*)d_in[12];
  const float* W2   = (const float*)d_in[13];
  const float* b2   = (const float*)d_in[14];

  const int N = in_sizes[0] / 128;
  const int E = in_sizes[2];
  const int nb = (N + 255) / 256;

  float* hout   = (float*)d_out;               // [N,128]
  float* logits = hout + (size_t)N*128;        // [N,40]

  // workspace layout
  unsigned short* xlr = (unsigned short*)d_ws; // N*256 bf16 (xl | xr per row)
  int2*  erec   = (int2*)(xlr + (size_t)N*256);// E records (src, w)
  int*   rowptr = (int*)(erec + E);            // N+1
  int*   cursor = rowptr + N + 1;              // N (doubles as deg)
  float* msum   = (float*)(cursor + N);        // 1
  int*   bsum   = (int*)(msum + 1);            // nb
  int*   boff   = bsum + nb;                   // nb
  float* bcat   = (float*)(boff + nb);         // 256
  unsigned short* wsp = (unsigned short*)(((uintptr_t)(bcat + 256) + 15) & ~(uintptr_t)15);
  unsigned short* Phi  = wsp;                  // 128*128
  unsigned short* Plo  = Phi + 16384;
  unsigned short* Lhi  = Plo + 16384;          // 256*128
  unsigned short* Llo  = Lhi + 32768;
  unsigned short* W1hi = Llo + 32768;          // 128*128
  unsigned short* W1lo = W1hi + 16384;
  unsigned short* W2hi = W1lo + 16384;         // 40*128
  unsigned short* W2lo = W2hi + 5120;

  hipMemsetAsync(cursor, 0, (size_t)(N + 1) * sizeof(int), stream);

  wprep<<<278, 256, 0, stream>>>(Wpre, Wl, Wr, W1, W2, bl, br,
                                 Phi, Plo, Lhi, Llo, W1hi, W1lo, W2hi, W2lo, bcat);
  count_mean<<<1024, 256, 0, stream>>>(ei, ew, cursor, msum, E);
  scan1_kernel<<<nb, 256, 0, stream>>>(cursor, rowptr, bsum, N);
  scan2_kernel<<<1, 512, 0, stream>>>(bsum, boff, nb);
  scan3_kernel<<<nb, 256, 0, stream>>>(rowptr, boff, N);
  hipMemcpyAsync(cursor, rowptr, (size_t)N * sizeof(int), hipMemcpyDeviceToDevice, stream);
  fill_kernel<<<(E + 255)/256, 256, 0, stream>>>(ei, ew, cursor, erec, E);

  const int gg = (N + 63) / 64;
  pre_kernel<<<gg, 512, 0, stream>>>(x, Phi, Plo, Lhi, Llo, bcat, hout, xlr, N);

  gather_kernel<<<(N + 3)/4, 256, 0, stream>>>(rowptr, erec, xlr, We, att, msum, bgat, hout, N);

  mlp_kernel<<<gg, 256, 0, stream>>>(hout, W1hi, W1lo, b1, W2hi, W2lo, b2, logits, N);
}

// Round 7
// 379.100 us; speedup vs baseline: 4.9759x; 1.1976x over previous
//
#include <hip/hip_runtime.h>

typedef __attribute__((ext_vector_type(8))) short short8;
typedef __attribute__((ext_vector_type(16))) float f32x16;

#if __has_builtin(__builtin_amdgcn_exp2f)
#define EXP2(x) __builtin_amdgcn_exp2f(x)
#else
#define EXP2(x) exp2f(x)
#endif

static __device__ __forceinline__ unsigned short f2bf(float f){
  unsigned u = __float_as_uint(f);
  unsigned r = u + 0x7fffu + ((u >> 16) & 1u);
  return (unsigned short)(r >> 16);
}
static __device__ __forceinline__ float bf2f(unsigned short h){
  return __uint_as_float(((unsigned)h) << 16);
}

// ---------------- all weight prep in one kernel ----------------
__global__ void wprep(const float* __restrict__ Wpre, const float* __restrict__ Wl,
                      const float* __restrict__ Wr, const float* __restrict__ W1,
                      const float* __restrict__ W2, const float* __restrict__ bl,
                      const float* __restrict__ br,
                      unsigned short* __restrict__ Phi, unsigned short* __restrict__ Plo,
                      unsigned short* __restrict__ Lhi, unsigned short* __restrict__ Llo,
                      unsigned short* __restrict__ W1hi, unsigned short* __restrict__ W1lo,
                      unsigned short* __restrict__ W2hi, unsigned short* __restrict__ W2lo,
                      float* __restrict__ bcat){
  int i = blockIdx.x*256 + threadIdx.x;
  float v; unsigned short* hp; unsigned short* lp; int oi;
  if (i < 16384){
    int c = i >> 7, k = i & 127;
    v = Wpre[(size_t)k*128 + c]; hp = Phi; lp = Plo; oi = i;
  } else if (i < 49152){
    int j = i - 16384; int c = j >> 7, k = j & 127;
    v = (c < 128) ? Wl[(size_t)k*128 + c] : Wr[(size_t)k*128 + (c-128)];
    hp = Lhi; lp = Llo; oi = j;
  } else if (i < 65536){
    int j = i - 49152; int c = j >> 7, k = j & 127;
    v = W1[(size_t)k*128 + c]; hp = W1hi; lp = W1lo; oi = j;
  } else if (i < 70656){
    int j = i - 65536; int c = j >> 7, k = j & 127;
    v = W2[(size_t)k*40 + c]; hp = W2hi; lp = W2lo; oi = j;
  } else if (i < 70912){
    int j = i - 70656;
    bcat[j] = (j < 128) ? bl[j] : br[j-128];
    return;
  } else return;
  unsigned short h = f2bf(v);
  hp[oi] = h;
  lp[oi] = f2bf(v - bf2f(h));
}

// ---------------- histogram + rank + mean in one pass ----------------
__global__ void count_mean(const int* __restrict__ ei, const float* __restrict__ ew,
                           int* __restrict__ deg, int* __restrict__ rk,
                           float* __restrict__ msum, int E){
  float s = 0.f;
  for (int e = blockIdx.x*256 + threadIdx.x; e < E; e += gridDim.x*256){
    rk[e] = atomicAdd(&deg[ei[E + e]], 1);
    s += ew[e];
  }
  for (int d = 32; d > 0; d >>= 1) s += __shfl_down(s, d, 64);
  __shared__ float ps[4];
  int lane = threadIdx.x & 63, w = threadIdx.x >> 6;
  if (lane == 0) ps[w] = s;
  __syncthreads();
  if (threadIdx.x == 0) atomicAdd(msum, (ps[0]+ps[1]+ps[2]+ps[3]) / (float)E);
}

// ---------------- scans ----------------
__global__ __launch_bounds__(256) void scan1_kernel(const int* __restrict__ deg, int* __restrict__ rowptr,
                                                    int* __restrict__ bsum, int N){
  __shared__ int s[256];
  int i = blockIdx.x*256 + threadIdx.x;
  int v = (i < N) ? deg[i] : 0;
  s[threadIdx.x] = v;
  __syncthreads();
  for (int off = 1; off < 256; off <<= 1){
    int t = (threadIdx.x >= off) ? s[threadIdx.x - off] : 0;
    __syncthreads();
    s[threadIdx.x] += t;
    __syncthreads();
  }
  if (i < N) rowptr[i + 1] = s[threadIdx.x];
  if (threadIdx.x == 255) bsum[blockIdx.x] = s[255];
}

__global__ __launch_bounds__(512) void scan2_kernel(const int* __restrict__ bsum, int* __restrict__ boff, int nb){
  __shared__ int s[512];
  int v = (threadIdx.x < nb) ? bsum[threadIdx.x] : 0;
  s[threadIdx.x] = v;
  __syncthreads();
  for (int off = 1; off < 512; off <<= 1){
    int t = (threadIdx.x >= off) ? s[threadIdx.x - off] : 0;
    __syncthreads();
    s[threadIdx.x] += t;
    __syncthreads();
  }
  if (threadIdx.x < nb) boff[threadIdx.x] = s[threadIdx.x] - v;
}

__global__ void scan3_kernel(int* __restrict__ rowptr, const int* __restrict__ boff, int N){
  int i = blockIdx.x*256 + threadIdx.x;
  if (i == 0) rowptr[0] = 0;
  if (i < N) rowptr[i + 1] += boff[i >> 8];
}

// rank-based scatter: no atomics
__global__ void fill_kernel(const int* __restrict__ ei, const float* __restrict__ ew,
                            const int* __restrict__ rowptr, const int* __restrict__ rk,
                            int2* __restrict__ erec, int E){
  int e = blockIdx.x*256 + threadIdx.x;
  if (e >= E) return;
  int dst = ei[E + e];
  erec[rowptr[dst] + rk[e]] = make_int2(ei[e], __float_as_int(ew[e]));
}

// ---------------- stage A tile (64x128 fp32 -> split bf16 LDS) ----------------
template<int NT>
static __device__ __forceinline__ void stageA(short* alds, const float* __restrict__ A,
                                              int row0, int N, int t){
  for (int g = t; g < 1024; g += NT){
    int r = g >> 4, k8 = g & 15;
    int grow = row0 + r;
    float4 p0, p1;
    if (grow < N){
      const float* ap = A + (size_t)grow*128 + k8*8;
      p0 = *(const float4*)ap;
      p1 = *(const float4*)(ap + 4);
    } else {
      p0 = make_float4(0.f,0.f,0.f,0.f); p1 = p0;
    }
    float vv[8] = {p0.x,p0.y,p0.z,p0.w,p1.x,p1.y,p1.z,p1.w};
    short8 hv, lv;
    #pragma unroll
    for (int j = 0; j < 8; ++j){
      unsigned short h = f2bf(vv[j]);
      hv[j] = (short)h;
      lv[j] = (short)f2bf(vv[j] - bf2f(h));
    }
    int slot = k8 ^ (r & 15);
    *(short8*)&alds[r*128 + slot*8] = hv;
    *(short8*)&alds[8192 + r*128 + slot*8] = lv;
  }
}

// 3-pass MFMA over two 32-row tiles, A from LDS, B frags in regs
#define MFMA_KLOOP(ACC0, ACC1) \
  _Pragma("unroll") \
  for (int ks = 0; ks < 8; ++ks){ \
    int k8 = ks*2 + kg; \
    const short* a0 = &alds[r0*128 + (k8 ^ sx)*8]; \
    const short* a1 = &alds[(r0+32)*128 + (k8 ^ sx)*8]; \
    short8 a0h = *(const short8*)a0; \
    short8 a0l = *(const short8*)(a0 + 8192); \
    short8 a1h = *(const short8*)a1; \
    short8 a1l = *(const short8*)(a1 + 8192); \
    ACC0 = __builtin_amdgcn_mfma_f32_32x32x16_bf16(a0h, bh[ks],  ACC0, 0,0,0); \
    ACC1 = __builtin_amdgcn_mfma_f32_32x32x16_bf16(a1h, bh[ks],  ACC1, 0,0,0); \
    ACC0 = __builtin_amdgcn_mfma_f32_32x32x16_bf16(a0l, bh[ks],  ACC0, 0,0,0); \
    ACC1 = __builtin_amdgcn_mfma_f32_32x32x16_bf16(a1l, bh[ks],  ACC1, 0,0,0); \
    ACC0 = __builtin_amdgcn_mfma_f32_32x32x16_bf16(a0h, bl8[ks], ACC0, 0,0,0); \
    ACC1 = __builtin_amdgcn_mfma_f32_32x32x16_bf16(a1h, bl8[ks], ACC1, 0,0,0); \
  }

// ---------------- fused pre: hout = x@Wpre (fp32) ; xlr = h0@[Wl|Wr]+bcat (bf16) ----------------
__global__ __launch_bounds__(512) void pre_kernel(
    const float* __restrict__ A,
    const unsigned short* __restrict__ Phi, const unsigned short* __restrict__ Plo,
    const unsigned short* __restrict__ Lhi, const unsigned short* __restrict__ Llo,
    const float* __restrict__ bcat,
    float* __restrict__ hout, unsigned short* __restrict__ xlr, int N)
{
  __shared__ short alds[2*64*128];
  const int t = threadIdx.x;
  const int row0 = blockIdx.x * 64;
  stageA<512>(alds, A, row0, N, t);
  __syncthreads();

  const int lane = t & 63, w = t >> 6;
  const int cl = lane & 31, kg = lane >> 5;
  const int sx = cl & 15;

  // ---- phase 1: h0 = x@Wpre ----
  {
    const int rt = w & 1, ct = w >> 1;
    const int colp = ct*32 + cl;
    short8 bh[8], bl8[8];
    #pragma unroll
    for (int ks = 0; ks < 8; ++ks){
      size_t off = (size_t)colp*128 + ks*16 + kg*8;
      bh[ks]  = *(const short8*)(Phi + off);
      bl8[ks] = *(const short8*)(Plo + off);
    }
    f32x16 acc;
    #pragma unroll
    for (int i = 0; i < 16; ++i) acc[i] = 0.f;
    const int r0 = rt*32 + cl;
    #pragma unroll
    for (int ks = 0; ks < 8; ++ks){
      int k8 = ks*2 + kg;
      const short* a = &alds[r0*128 + (k8 ^ sx)*8];
      short8 ah = *(const short8*)a;
      short8 al = *(const short8*)(a + 8192);
      acc = __builtin_amdgcn_mfma_f32_32x32x16_bf16(ah, bh[ks],  acc, 0,0,0);
      acc = __builtin_amdgcn_mfma_f32_32x32x16_bf16(al, bh[ks],  acc, 0,0,0);
      acc = __builtin_amdgcn_mfma_f32_32x32x16_bf16(ah, bl8[ks], acc, 0,0,0);
    }
    __syncthreads();
    #pragma unroll
    for (int reg = 0; reg < 16; ++reg){
      int row = rt*32 + (reg & 3) + 8*(reg >> 2) + 4*kg;
      float v = acc[reg];
      int grow = row0 + row;
      if (grow < N) hout[(size_t)grow*128 + colp] = v;
      unsigned short h = f2bf(v);
      unsigned short l = f2bf(v - bf2f(h));
      int idx = row*128 + (((colp >> 3) ^ (row & 15)) << 3) + (colp & 7);
      alds[idx] = (short)h;
      alds[8192 + idx] = (short)l;
    }
  }
  __syncthreads();

  // ---- phase 2: xlr = h0 @ [Wl|Wr] + bcat ----
  {
    const int col = w*32 + cl;
    short8 bh[8], bl8[8];
    #pragma unroll
    for (int ks = 0; ks < 8; ++ks){
      size_t off = (size_t)col*128 + ks*16 + kg*8;
      bh[ks]  = *(const short8*)(Lhi + off);
      bl8[ks] = *(const short8*)(Llo + off);
    }
    f32x16 acc0, acc1;
    #pragma unroll
    for (int i = 0; i < 16; ++i){ acc0[i] = 0.f; acc1[i] = 0.f; }
    const int r0 = cl;
    MFMA_KLOOP(acc0, acc1)
    float bv = bcat[col];
    #pragma unroll
    for (int rt2 = 0; rt2 < 2; ++rt2){
      const f32x16& ac = rt2 ? acc1 : acc0;
      #pragma unroll
      for (int reg = 0; reg < 16; ++reg){
        int row = rt2*32 + (reg & 3) + 8*(reg >> 2) + 4*kg;
        int grow = row0 + row;
        if (grow < N) xlr[(size_t)grow*256 + col] = f2bf(ac[reg] + bv);
      }
    }
  }
}

// ---------------- fused MLP: logits = relu(h@W1+b1)@W2 + b2 ----------------
__global__ __launch_bounds__(256) void mlp_kernel(
    const float* __restrict__ A,
    const unsigned short* __restrict__ B1hi, const unsigned short* __restrict__ B1lo,
    const float* __restrict__ b1,
    const unsigned short* __restrict__ B2hi, const unsigned short* __restrict__ B2lo,
    const float* __restrict__ b2,
    float* __restrict__ logits, int N)
{
  __shared__ short alds[2*64*128];
  const int t = threadIdx.x;
  const int row0 = blockIdx.x * 64;
  stageA<256>(alds, A, row0, N, t);
  __syncthreads();

  const int lane = t & 63, w = t >> 6;
  const int cl = lane & 31, kg = lane >> 5;
  const int r0 = cl;
  const int sx = r0 & 15;

  {
    const int col = w*32 + cl;
    short8 bh[8], bl8[8];
    #pragma unroll
    for (int ks = 0; ks < 8; ++ks){
      size_t off = (size_t)col*128 + ks*16 + kg*8;
      bh[ks]  = *(const short8*)(B1hi + off);
      bl8[ks] = *(const short8*)(B1lo + off);
    }
    f32x16 acc0, acc1;
    #pragma unroll
    for (int i = 0; i < 16; ++i){ acc0[i] = 0.f; acc1[i] = 0.f; }
    MFMA_KLOOP(acc0, acc1)

    float bv = b1[col];
    __syncthreads();
    #pragma unroll
    for (int rt = 0; rt < 2; ++rt){
      const f32x16& ac = rt ? acc1 : acc0;
      #pragma unroll
      for (int reg = 0; reg < 16; ++reg){
        int row = rt*32 + (reg & 3) + 8*(reg >> 2) + 4*kg;
        float v = fmaxf(ac[reg] + bv, 0.f);
        unsigned short h = f2bf(v);
        unsigned short l = f2bf(v - bf2f(h));
        int idx = row*128 + (((col >> 3) ^ (row & 15)) << 3) + (col & 7);
        alds[idx] = (short)h;
        alds[8192 + idx] = (short)l;
      }
    }
    __syncthreads();
  }

  if (w < 2){
    const int col = w*32 + cl;
    const bool cok = col < 40;
    short8 bh[8], bl8[8];
    #pragma unroll
    for (int ks = 0; ks < 8; ++ks){
      if (cok){
        size_t off = (size_t)col*128 + ks*16 + kg*8;
        bh[ks]  = *(const short8*)(B2hi + off);
        bl8[ks] = *(const short8*)(B2lo + off);
      } else {
        #pragma unroll
        for (int j = 0; j < 8; ++j){ bh[ks][j] = 0; bl8[ks][j] = 0; }
      }
    }
    f32x16 acc0, acc1;
    #pragma unroll
    for (int i = 0; i < 16; ++i){ acc0[i] = 0.f; acc1[i] = 0.f; }
    MFMA_KLOOP(acc0, acc1)

    if (cok){
      float bv = b2[col];
      #pragma unroll
      for (int rt = 0; rt < 2; ++rt){
        const f32x16& ac = rt ? acc1 : acc0;
        #pragma unroll
        for (int reg = 0; reg < 16; ++reg){
          int row = rt*32 + (reg & 3) + 8*(reg >> 2) + 4*kg;
          int grow = row0 + row;
          if (grow < N) logits[(size_t)grow*40 + col] = ac[reg] + bv;
        }
      }
    }
  }
}

// ---------------- gather: 4 edges/wave x 16 lanes/edge, LDS records + depth-4 pipeline ----------------
__global__ __launch_bounds__(256) void gather_kernel(
    const int* __restrict__ rowptr, const int2* __restrict__ erec,
    const unsigned short* __restrict__ xlr,     // [N][256] bf16: xl | xr
    const float* __restrict__ We, const float* __restrict__ att,
    const float* __restrict__ msum, const float* __restrict__ bgat,
    float* __restrict__ hbuf, int N)
{
  __shared__ int2 recs[4][64];                  // wave-private record slab
  const int wid  = threadIdx.x >> 6;
  const int lane = threadIdx.x & 63;
  const int n = blockIdx.x * 4 + wid;
  if (n >= N) return;

  const int g   = lane >> 4;      // edge slot 0..3
  const int l   = lane & 15;      // channels [l*8, l*8+8)
  const int ch0 = l * 8;
  int2* myrec = &recs[wid][0];

  float xrv[8], wev[8], at6[8], at4[8];
  {
    short8 q = *(const short8*)&xlr[(size_t)n*256 + 128 + ch0];
    float4 w0 = *(const float4*)&We[ch0];
    float4 w1 = *(const float4*)&We[ch0+4];
    float4 a0 = *(const float4*)&att[ch0];
    float4 a1 = *(const float4*)&att[ch0+4];
    const float L2E = 1.4426950408889634f;
    float wv[8] = {w0.x,w0.y,w0.z,w0.w,w1.x,w1.y,w1.z,w1.w};
    float av[8] = {a0.x,a0.y,a0.z,a0.w,a1.x,a1.y,a1.z,a1.w};
    #pragma unroll
    for (int j = 0; j < 8; ++j){
      xrv[j] = bf2f((unsigned short)q[j]);
      wev[j] = wv[j];
      at6[j] = av[j]*0.6f*L2E;    // lrelu(z) = 0.6z + 0.4|z|, fold log2(e)
      at4[j] = av[j]*0.4f*L2E;
    }
  }

  float num[8];
  #pragma unroll
  for (int j = 0; j < 8; ++j) num[j] = 0.f;
  float den = 0.f;

  const int beg = rowptr[n], end = rowptr[n + 1];   // self slot at 'end'
  const int2 selfrec = make_int2(n, msum[0] == 0.f ? 0 : __float_as_int(msum[0]));

  for (int seg = beg; seg <= end; seg += 64){
    // coalesced burst -> wave-private LDS (in-order DS pipe; no barrier needed)
    int idx = seg + lane;
    myrec[lane] = (idx < end) ? erec[idx] : selfrec;

    const int rem = end - seg;                       // self slot local index (if < 64)
    const int m = (rem + 1 < 64) ? rem + 1 : 64;     // active slots this segment
    const int nIter = (m + 3) >> 2;

    // record regs 5 ahead, pv loads 4 ahead
    int2 R0 = myrec[g], R1 = myrec[4+g], R2 = myrec[8+g], R3 = myrec[12+g], R4 = myrec[16+g];
    short8 P0 = *(const short8*)&xlr[(size_t)R0.x*256 + ch0];
    short8 P1 = *(const short8*)&xlr[(size_t)R1.x*256 + ch0];
    short8 P2 = *(const short8*)&xlr[(size_t)R2.x*256 + ch0];
    short8 P3 = *(const short8*)&xlr[(size_t)R3.x*256 + ch0];

    #pragma unroll 4
    for (int t = 0; t < nIter; ++t){
      const int slot = t*4 + g;
      const bool act = slot < m;                     // real edge or self
      const float wj = __int_as_float(R0.y);

      float xlv[8];
      #pragma unroll
      for (int q = 0; q < 8; ++q) xlv[q] = bf2f((unsigned short)P0[q]);

      float p = 0.f;
      #pragma unroll
      for (int q = 0; q < 8; ++q){
        float z = fmaf(wj, wev[q], xlv[q] + xrv[q]);
        p = fmaf(at6[q], z, p);
        p = fmaf(at4[q], fabsf(z), p);
      }
      p += __shfl_xor(p, 1, 64);
      p += __shfl_xor(p, 2, 64);
      float ex = act ? EXP2(p) : 0.f;
      den += ex;
      #pragma unroll
      for (int q = 0; q < 8; ++q) num[q] = fmaf(ex, xlv[q], num[q]);

      // rotate pipeline
      R0 = R1; R1 = R2; R2 = R3; R3 = R4;
      R4 = myrec[((t+5)*4 + g) & 63];
      P0 = P1; P1 = P2; P2 = P3;
      P3 = *(const short8*)&xlr[(size_t)R3.x*256 + ch0];
    }
  }

  #pragma unroll
  for (int j = 0; j < 8; ++j){
    num[j] += __shfl_xor(num[j], 16, 64);
    num[j] += __shfl_xor(num[j], 32, 64);
  }
  den += __shfl_xor(den, 16, 64);
  den += __shfl_xor(den, 32, 64);

  if (g == 0){
    float inv = 1.f / (den + 1e-16f);
    float o[8];
    #pragma unroll
    for (int j = 0; j < 8; ++j){
      float v = num[j]*inv + bgat[ch0+j];
      o[j] = v > 0.f ? v : expm1f(v);   // ELU
    }
    float4 h0a = *(const float4*)&hbuf[(size_t)n*128 + ch0];
    float4 h0b = *(const float4*)&hbuf[(size_t)n*128 + ch0 + 4];
    h0a.x += o[0]; h0a.y += o[1]; h0a.z += o[2]; h0a.w += o[3];
    h0b.x += o[4]; h0b.y += o[5]; h0b.z += o[6]; h0b.w += o[7];
    *(float4*)&hbuf[(size_t)n*128 + ch0]     = h0a;
    *(float4*)&hbuf[(size_t)n*128 + ch0 + 4] = h0b;
  }
}

extern "C" void kernel_launch(void* const* d_in, const int* in_sizes, int n_in,
                              void* d_out, int out_size, void* d_ws, size_t ws_size,
                              hipStream_t stream)
{
  const float* x    = (const float*)d_in[0];
  const int*   ei   = (const int*)  d_in[1];
  const float* ew   = (const float*)d_in[2];
  const float* Wpre = (const float*)d_in[3];
  const float* Wl   = (const float*)d_in[4];
  const float* bl   = (const float*)d_in[5];
  const float* Wr   = (const float*)d_in[6];
  const float* br   = (const float*)d_in[7];
  const float* We   = (const float*)d_in[8];
  const float* att  = (const float*)d_in[9];
  const float* bgat = (const float*)d_in[10];
  const float* W1   = (const float*)d_in[11];
  const float* b1   = (const float*)d_in[12];
  const float* W2   = (const float*)d_in[13];
  const float* b2   = (const float*)d_in[14];

  const int N = in_sizes[0] / 128;
  const int E = in_sizes[2];
  const int nb = (N + 255) / 256;

  float* hout   = (float*)d_out;               // [N,128]
  float* logits = hout + (size_t)N*128;        // [N,40]

  // workspace layout
  unsigned short* xlr = (unsigned short*)d_ws; // N*256 bf16 (xl | xr per row)
  int2*  erec   = (int2*)(xlr + (size_t)N*256);// E records (src, w)
  int*   rk     = (int*)(erec + E);            // E ranks
  int*   rowptr = rk + E;                      // N+1
  int*   cursor = rowptr + N + 1;              // N (deg)
  float* msum   = (float*)(cursor + N);        // 1
  int*   bsum   = (int*)(msum + 1);            // nb
  int*   boff   = bsum + nb;                   // nb
  float* bcat   = (float*)(boff + nb);         // 256
  unsigned short* wsp = (unsigned short*)(((uintptr_t)(bcat + 256) + 15) & ~(uintptr_t)15);
  unsigned short* Phi  = wsp;                  // 128*128
  unsigned short* Plo  = Phi + 16384;
  unsigned short* Lhi  = Plo + 16384;          // 256*128
  unsigned short* Llo  = Lhi + 32768;
  unsigned short* W1hi = Llo + 32768;          // 128*128
  unsigned short* W1lo = W1hi + 16384;
  unsigned short* W2hi = W1lo + 16384;         // 40*128
  unsigned short* W2lo = W2hi + 5120;

  hipMemsetAsync(cursor, 0, (size_t)(N + 1) * sizeof(int), stream);

  wprep<<<278, 256, 0, stream>>>(Wpre, Wl, Wr, W1, W2, bl, br,
                                 Phi, Plo, Lhi, Llo, W1hi, W1lo, W2hi, W2lo, bcat);
  count_mean<<<1024, 256, 0, stream>>>(ei, ew, cursor, rk, msum, E);
  scan1_kernel<<<nb, 256, 0, stream>>>(cursor, rowptr, bsum, N);
  scan2_kernel<<<1, 512, 0, stream>>>(bsum, boff, nb);
  scan3_kernel<<<nb, 256, 0, stream>>>(rowptr, boff, N);
  fill_kernel<<<(E + 255)/256, 256, 0, stream>>>(ei, ew, rowptr, rk, erec, E);

  const int gg = (N + 63) / 64;
  pre_kernel<<<gg, 512, 0, stream>>>(x, Phi, Plo, Lhi, Llo, bcat, hout, xlr, N);

  gather_kernel<<<(N + 3)/4, 256, 0, stream>>>(rowptr, erec, xlr, We, att, msum, bgat, hout, N);

  mlp_kernel<<<gg, 256, 0, stream>>>(hout, W1hi, W1lo, b1, W2hi, W2lo, b2, logits, N);
}

// Round 9
// 341.215 us; speedup vs baseline: 5.5283x; 1.1110x over previous
//
#include <hip/hip_runtime.h>

typedef __attribute__((ext_vector_type(8))) short short8;
typedef __attribute__((ext_vector_type(16))) float f32x16;

#if __has_builtin(__builtin_amdgcn_exp2f)
#define EXP2(x) __builtin_amdgcn_exp2f(x)
#else
#define EXP2(x) exp2f(x)
#endif

static __device__ __forceinline__ unsigned short f2bf(float f){
  unsigned u = __float_as_uint(f);
  unsigned r = u + 0x7fffu + ((u >> 16) & 1u);
  return (unsigned short)(r >> 16);
}
static __device__ __forceinline__ float bf2f(unsigned short h){
  return __uint_as_float(((unsigned)h) << 16);
}

// ---------------- all weight prep in one kernel ----------------
__global__ void wprep(const float* __restrict__ Wpre, const float* __restrict__ Wl,
                      const float* __restrict__ Wr, const float* __restrict__ W1,
                      const float* __restrict__ W2, const float* __restrict__ bl,
                      const float* __restrict__ br,
                      unsigned short* __restrict__ Phi, unsigned short* __restrict__ Plo,
                      unsigned short* __restrict__ Lhi, unsigned short* __restrict__ Llo,
                      unsigned short* __restrict__ W1hi, unsigned short* __restrict__ W1lo,
                      unsigned short* __restrict__ W2hi, unsigned short* __restrict__ W2lo,
                      float* __restrict__ bcat){
  int i = blockIdx.x*256 + threadIdx.x;
  float v; unsigned short* hp; unsigned short* lp; int oi;
  if (i < 16384){
    int c = i >> 7, k = i & 127;
    v = Wpre[(size_t)k*128 + c]; hp = Phi; lp = Plo; oi = i;
  } else if (i < 49152){
    int j = i - 16384; int c = j >> 7, k = j & 127;
    v = (c < 128) ? Wl[(size_t)k*128 + c] : Wr[(size_t)k*128 + (c-128)];
    hp = Lhi; lp = Llo; oi = j;
  } else if (i < 65536){
    int j = i - 49152; int c = j >> 7, k = j & 127;
    v = W1[(size_t)k*128 + c]; hp = W1hi; lp = W1lo; oi = j;
  } else if (i < 70656){
    int j = i - 65536; int c = j >> 7, k = j & 127;
    v = W2[(size_t)k*40 + c]; hp = W2hi; lp = W2lo; oi = j;
  } else if (i < 70912){
    int j = i - 70656;
    bcat[j] = (j < 128) ? bl[j] : br[j-128];
    return;
  } else return;
  unsigned short h = f2bf(v);
  hp[oi] = h;
  lp[oi] = f2bf(v - bf2f(h));
}

// ---------------- histogram + rank + mean in one pass ----------------
__global__ void count_mean(const int* __restrict__ ei, const float* __restrict__ ew,
                           int* __restrict__ deg, int* __restrict__ rk,
                           float* __restrict__ msum, int E){
  float s = 0.f;
  for (int e = blockIdx.x*256 + threadIdx.x; e < E; e += gridDim.x*256){
    rk[e] = atomicAdd(&deg[ei[E + e]], 1);
    s += ew[e];
  }
  for (int d = 32; d > 0; d >>= 1) s += __shfl_down(s, d, 64);
  __shared__ float ps[4];
  int lane = threadIdx.x & 63, w = threadIdx.x >> 6;
  if (lane == 0) ps[w] = s;
  __syncthreads();
  if (threadIdx.x == 0) atomicAdd(msum, (ps[0]+ps[1]+ps[2]+ps[3]) / (float)E);
}

// ---------------- scans ----------------
__global__ __launch_bounds__(256) void scan1_kernel(const int* __restrict__ deg, int* __restrict__ rowptr,
                                                    int* __restrict__ bsum, int N){
  __shared__ int s[256];
  int i = blockIdx.x*256 + threadIdx.x;
  int v = (i < N) ? deg[i] : 0;
  s[threadIdx.x] = v;
  __syncthreads();
  for (int off = 1; off < 256; off <<= 1){
    int t = (threadIdx.x >= off) ? s[threadIdx.x - off] : 0;
    __syncthreads();
    s[threadIdx.x] += t;
    __syncthreads();
  }
  if (i < N) rowptr[i + 1] = s[threadIdx.x];
  if (threadIdx.x == 255) bsum[blockIdx.x] = s[255];
}

__global__ __launch_bounds__(512) void scan2_kernel(const int* __restrict__ bsum, int* __restrict__ boff, int nb){
  __shared__ int s[512];
  int v = (threadIdx.x < nb) ? bsum[threadIdx.x] : 0;
  s[threadIdx.x] = v;
  __syncthreads();
  for (int off = 1; off < 512; off <<= 1){
    int t = (threadIdx.x >= off) ? s[threadIdx.x - off] : 0;
    __syncthreads();
    s[threadIdx.x] += t;
    __syncthreads();
  }
  if (threadIdx.x < nb) boff[threadIdx.x] = s[threadIdx.x] - v;
}

__global__ void scan3_kernel(int* __restrict__ rowptr, const int* __restrict__ boff, int N){
  int i = blockIdx.x*256 + threadIdx.x;
  if (i == 0) rowptr[0] = 0;
  if (i < N) rowptr[i + 1] += boff[i >> 8];
}

// rank-based scatter: no atomics
__global__ void fill_kernel(const int* __restrict__ ei, const float* __restrict__ ew,
                            const int* __restrict__ rowptr, const int* __restrict__ rk,
                            int2* __restrict__ erec, int E){
  int e = blockIdx.x*256 + threadIdx.x;
  if (e >= E) return;
  int dst = ei[E + e];
  erec[rowptr[dst] + rk[e]] = make_int2(ei[e], __float_as_int(ew[e]));
}

// ---------------- stage A tile (64x128 fp32 -> split bf16 LDS) ----------------
template<int NT>
static __device__ __forceinline__ void stageA(short* alds, const float* __restrict__ A,
                                              int row0, int N, int t){
  for (int g = t; g < 1024; g += NT){
    int r = g >> 4, k8 = g & 15;
    int grow = row0 + r;
    float4 p0, p1;
    if (grow < N){
      const float* ap = A + (size_t)grow*128 + k8*8;
      p0 = *(const float4*)ap;
      p1 = *(const float4*)(ap + 4);
    } else {
      p0 = make_float4(0.f,0.f,0.f,0.f); p1 = p0;
    }
    float vv[8] = {p0.x,p0.y,p0.z,p0.w,p1.x,p1.y,p1.z,p1.w};
    short8 hv, lv;
    #pragma unroll
    for (int j = 0; j < 8; ++j){
      unsigned short h = f2bf(vv[j]);
      hv[j] = (short)h;
      lv[j] = (short)f2bf(vv[j] - bf2f(h));
    }
    int slot = k8 ^ (r & 15);
    *(short8*)&alds[r*128 + slot*8] = hv;
    *(short8*)&alds[8192 + r*128 + slot*8] = lv;
  }
}

// 3-pass MFMA over two 32-row tiles, A from LDS, B frags in regs
#define MFMA_KLOOP(ACC0, ACC1) \
  _Pragma("unroll") \
  for (int ks = 0; ks < 8; ++ks){ \
    int k8 = ks*2 + kg; \
    const short* a0 = &alds[r0*128 + (k8 ^ sx)*8]; \
    const short* a1 = &alds[(r0+32)*128 + (k8 ^ sx)*8]; \
    short8 a0h = *(const short8*)a0; \
    short8 a0l = *(const short8*)(a0 + 8192); \
    short8 a1h = *(const short8*)a1; \
    short8 a1l = *(const short8*)(a1 + 8192); \
    ACC0 = __builtin_amdgcn_mfma_f32_32x32x16_bf16(a0h, bh[ks],  ACC0, 0,0,0); \
    ACC1 = __builtin_amdgcn_mfma_f32_32x32x16_bf16(a1h, bh[ks],  ACC1, 0,0,0); \
    ACC0 = __builtin_amdgcn_mfma_f32_32x32x16_bf16(a0l, bh[ks],  ACC0, 0,0,0); \
    ACC1 = __builtin_amdgcn_mfma_f32_32x32x16_bf16(a1l, bh[ks],  ACC1, 0,0,0); \
    ACC0 = __builtin_amdgcn_mfma_f32_32x32x16_bf16(a0h, bl8[ks], ACC0, 0,0,0); \
    ACC1 = __builtin_amdgcn_mfma_f32_32x32x16_bf16(a1h, bl8[ks], ACC1, 0,0,0); \
  }

// ---------------- fused pre: hout = x@Wpre (fp32) ; xlr = h0@[Wl|Wr]+bcat (bf16) ----------------
__global__ __launch_bounds__(512) void pre_kernel(
    const float* __restrict__ A,
    const unsigned short* __restrict__ Phi, const unsigned short* __restrict__ Plo,
    const unsigned short* __restrict__ Lhi, const unsigned short* __restrict__ Llo,
    const float* __restrict__ bcat,
    float* __restrict__ hout, unsigned short* __restrict__ xlr, int N)
{
  __shared__ short alds[2*64*128];
  const int t = threadIdx.x;
  const int row0 = blockIdx.x * 64;
  stageA<512>(alds, A, row0, N, t);
  __syncthreads();

  const int lane = t & 63, w = t >> 6;
  const int cl = lane & 31, kg = lane >> 5;
  const int sx = cl & 15;

  // ---- phase 1: h0 = x@Wpre ----
  {
    const int rt = w & 1, ct = w >> 1;
    const int colp = ct*32 + cl;
    short8 bh[8], bl8[8];
    #pragma unroll
    for (int ks = 0; ks < 8; ++ks){
      size_t off = (size_t)colp*128 + ks*16 + kg*8;
      bh[ks]  = *(const short8*)(Phi + off);
      bl8[ks] = *(const short8*)(Plo + off);
    }
    f32x16 acc;
    #pragma unroll
    for (int i = 0; i < 16; ++i) acc[i] = 0.f;
    const int r0 = rt*32 + cl;
    #pragma unroll
    for (int ks = 0; ks < 8; ++ks){
      int k8 = ks*2 + kg;
      const short* a = &alds[r0*128 + (k8 ^ sx)*8];
      short8 ah = *(const short8*)a;
      short8 al = *(const short8*)(a + 8192);
      acc = __builtin_amdgcn_mfma_f32_32x32x16_bf16(ah, bh[ks],  acc, 0,0,0);
      acc = __builtin_amdgcn_mfma_f32_32x32x16_bf16(al, bh[ks],  acc, 0,0,0);
      acc = __builtin_amdgcn_mfma_f32_32x32x16_bf16(ah, bl8[ks], acc, 0,0,0);
    }
    __syncthreads();
    #pragma unroll
    for (int reg = 0; reg < 16; ++reg){
      int row = rt*32 + (reg & 3) + 8*(reg >> 2) + 4*kg;
      float v = acc[reg];
      int grow = row0 + row;
      if (grow < N) hout[(size_t)grow*128 + colp] = v;
      unsigned short h = f2bf(v);
      unsigned short l = f2bf(v - bf2f(h));
      int idx = row*128 + (((colp >> 3) ^ (row & 15)) << 3) + (colp & 7);
      alds[idx] = (short)h;
      alds[8192 + idx] = (short)l;
    }
  }
  __syncthreads();

  // ---- phase 2: xlr = h0 @ [Wl|Wr] + bcat ----
  {
    const int col = w*32 + cl;
    short8 bh[8], bl8[8];
    #pragma unroll
    for (int ks = 0; ks < 8; ++ks){
      size_t off = (size_t)col*128 + ks*16 + kg*8;
      bh[ks]  = *(const short8*)(Lhi + off);
      bl8[ks] = *(const short8*)(Llo + off);
    }
    f32x16 acc0, acc1;
    #pragma unroll
    for (int i = 0; i < 16; ++i){ acc0[i] = 0.f; acc1[i] = 0.f; }
    const int r0 = cl;
    MFMA_KLOOP(acc0, acc1)
    float bv = bcat[col];
    #pragma unroll
    for (int rt2 = 0; rt2 < 2; ++rt2){
      const f32x16& ac = rt2 ? acc1 : acc0;
      #pragma unroll
      for (int reg = 0; reg < 16; ++reg){
        int row = rt2*32 + (reg & 3) + 8*(reg >> 2) + 4*kg;
        int grow = row0 + row;
        if (grow < N) xlr[(size_t)grow*256 + col] = f2bf(ac[reg] + bv);
      }
    }
  }
}

// ---------------- fused MLP: logits = relu(h@W1+b1)@W2 + b2 ----------------
__global__ __launch_bounds__(256) void mlp_kernel(
    const float* __restrict__ A,
    const unsigned short* __restrict__ B1hi, const unsigned short* __restrict__ B1lo,
    const float* __restrict__ b1,
    const unsigned short* __restrict__ B2hi, const unsigned short* __restrict__ B2lo,
    const float* __restrict__ b2,
    float* __restrict__ logits, int N)
{
  __shared__ short alds[2*64*128];
  const int t = threadIdx.x;
  const int row0 = blockIdx.x * 64;
  stageA<256>(alds, A, row0, N, t);
  __syncthreads();

  const int lane = t & 63, w = t >> 6;
  const int cl = lane & 31, kg = lane >> 5;
  const int r0 = cl;
  const int sx = r0 & 15;

  {
    const int col = w*32 + cl;
    short8 bh[8], bl8[8];
    #pragma unroll
    for (int ks = 0; ks < 8; ++ks){
      size_t off = (size_t)col*128 + ks*16 + kg*8;
      bh[ks]  = *(const short8*)(B1hi + off);
      bl8[ks] = *(const short8*)(B1lo + off);
    }
    f32x16 acc0, acc1;
    #pragma unroll
    for (int i = 0; i < 16; ++i){ acc0[i] = 0.f; acc1[i] = 0.f; }
    MFMA_KLOOP(acc0, acc1)

    float bv = b1[col];
    __syncthreads();
    #pragma unroll
    for (int rt = 0; rt < 2; ++rt){
      const f32x16& ac = rt ? acc1 : acc0;
      #pragma unroll
      for (int reg = 0; reg < 16; ++reg){
        int row = rt*32 + (reg & 3) + 8*(reg >> 2) + 4*kg;
        float v = fmaxf(ac[reg] + bv, 0.f);
        unsigned short h = f2bf(v);
        unsigned short l = f2bf(v - bf2f(h));
        int idx = row*128 + (((col >> 3) ^ (row & 15)) << 3) + (col & 7);
        alds[idx] = (short)h;
        alds[8192 + idx] = (short)l;
      }
    }
    __syncthreads();
  }

  if (w < 2){
    const int col = w*32 + cl;
    const bool cok = col < 40;
    short8 bh[8], bl8[8];
    #pragma unroll
    for (int ks = 0; ks < 8; ++ks){
      if (cok){
        size_t off = (size_t)col*128 + ks*16 + kg*8;
        bh[ks]  = *(const short8*)(B2hi + off);
        bl8[ks] = *(const short8*)(B2lo + off);
      } else {
        #pragma unroll
        for (int j = 0; j < 8; ++j){ bh[ks][j] = 0; bl8[ks][j] = 0; }
      }
    }
    f32x16 acc0, acc1;
    #pragma unroll
    for (int i = 0; i < 16; ++i){ acc0[i] = 0.f; acc1[i] = 0.f; }
    MFMA_KLOOP(acc0, acc1)

    if (cok){
      float bv = b2[col];
      #pragma unroll
      for (int rt = 0; rt < 2; ++rt){
        const f32x16& ac = rt ? acc1 : acc0;
        #pragma unroll
        for (int reg = 0; reg < 16; ++reg){
          int row = rt*32 + (reg & 3) + 8*(reg >> 2) + 4*kg;
          int grow = row0 + row;
          if (grow < N) logits[(size_t)grow*40 + col] = ac[reg] + bv;
        }
      }
    }
  }
}

// ---------------- gather: 4 INDEPENDENT nodes/wave (one per 16-lane group) ----------------
// lane layout: group g = lane>>4 owns node base+g; lane l = lane&15 owns channels [l*8, l*8+8)
__global__ __launch_bounds__(256) void gather_kernel(
    const int* __restrict__ rowptr, const int2* __restrict__ erec,
    const unsigned short* __restrict__ xlr,     // [N][256] bf16: xl | xr
    const float* __restrict__ We, const float* __restrict__ att,
    const float* __restrict__ msum, const float* __restrict__ bgat,
    float* __restrict__ hbuf, int N)
{
  const int wid  = threadIdx.x >> 6;
  const int lane = threadIdx.x & 63;
  const int g    = lane >> 4;
  const int l    = lane & 15;
  const int ch0  = l * 8;
  const int n    = (blockIdx.x*4 + wid)*4 + g;
  const bool nok = n < N;

  // per-node constants (8 channels per lane)
  float xrv[8], wev[8], at6[8], at4[8];
  {
    short8 q = (short8)0;
    if (nok) q = *(const short8*)&xlr[(size_t)n*256 + 128 + ch0];
    float4 w0 = *(const float4*)&We[ch0];
    float4 w1 = *(const float4*)&We[ch0+4];
    float4 a0 = *(const float4*)&att[ch0];
    float4 a1 = *(const float4*)&att[ch0+4];
    const float L2E = 1.4426950408889634f;
    float wv[8] = {w0.x,w0.y,w0.z,w0.w,w1.x,w1.y,w1.z,w1.w};
    float av[8] = {a0.x,a0.y,a0.z,a0.w,a1.x,a1.y,a1.z,a1.w};
    #pragma unroll
    for (int j = 0; j < 8; ++j){
      xrv[j] = bf2f((unsigned short)q[j]);
      wev[j] = wv[j];
      at6[j] = av[j]*0.6f*L2E;    // lrelu(z) = 0.6z + 0.4|z|, fold log2(e)
      at4[j] = av[j]*0.4f*L2E;
    }
  }

  float num[8];
  #pragma unroll
  for (int j = 0; j < 8; ++j) num[j] = 0.f;
  float den = 0.f;

  const float wm = msum[0];
  int beg = 0, end = 0;
  if (nok){ beg = rowptr[n]; end = rowptr[n + 1]; }
  const int cnt = nok ? (end - beg + 1) : 0;   // +1 for self loop

  // wave iteration count = max over the 4 groups
  int itMax = cnt;
  itMax = max(itMax, __shfl_xor(itMax, 16, 64));
  itMax = max(itMax, __shfl_xor(itMax, 32, 64));

  const int2 selfrec = make_int2(nok ? n : 0, __float_as_int(wm));
  int pos = beg;
  int2 rec = (nok && beg < end) ? erec[beg] : selfrec;

  for (int it = 0; it < itMax; ++it){
    // prefetch next record (1 iteration ahead; uniform across the 16-lane group)
    int np = pos + 1;
    int2 recN = (np < end) ? erec[np] : selfrec;

    const bool act = it < cnt;
    short8 pv = *(const short8*)&xlr[(size_t)rec.x*256 + ch0];
    const float wj = __int_as_float(rec.y);

    float xlv[8];
    #pragma unroll
    for (int q = 0; q < 8; ++q) xlv[q] = bf2f((unsigned short)pv[q]);

    float p = 0.f;
    #pragma unroll
    for (int q = 0; q < 8; ++q){
      float z = fmaf(wj, wev[q], xlv[q] + xrv[q]);
      p = fmaf(at6[q], z, p);
      p = fmaf(at4[q], fabsf(z), p);
    }
    p += __shfl_xor(p, 1, 64);
    p += __shfl_xor(p, 2, 64);     // per-head alpha*log2e within 4-lane subgroup
    float ex = act ? EXP2(p) : 0.f;
    den += ex;
    #pragma unroll
    for (int q = 0; q < 8; ++q) num[q] = fmaf(ex, xlv[q], num[q]);

    rec = recN; pos = np;
  }

  if (nok){
    float inv = 1.f / (den + 1e-16f);
    float o[8];
    #pragma unroll
    for (int j = 0; j < 8; ++j){
      float v = num[j]*inv + bgat[ch0+j];
      o[j] = v > 0.f ? v : expm1f(v);   // ELU
    }
    float4 h0a = *(const float4*)&hbuf[(size_t)n*128 + ch0];
    float4 h0b = *(const float4*)&hbuf[(size_t)n*128 + ch0 + 4];
    h0a.x += o[0]; h0a.y += o[1]; h0a.z += o[2]; h0a.w += o[3];
    h0b.x += o[4]; h0b.y += o[5]; h0b.z += o[6]; h0b.w += o[7];
    *(float4*)&hbuf[(size_t)n*128 + ch0]     = h0a;
    *(float4*)&hbuf[(size_t)n*128 + ch0 + 4] = h0b;
  }
}

extern "C" void kernel_launch(void* const* d_in, const int* in_sizes, int n_in,
                              void* d_out, int out_size, void* d_ws, size_t ws_size,
                              hipStream_t stream)
{
  const float* x    = (const float*)d_in[0];
  const int*   ei   = (const int*)  d_in[1];
  const float* ew   = (const float*)d_in[2];
  const float* Wpre = (const float*)d_in[3];
  const float* Wl   = (const float*)d_in[4];
  const float* bl   = (const float*)d_in[5];
  const float* Wr   = (const float*)d_in[6];
  const float* br   = (const float*)d_in[7];
  const float* We   = (const float*)d_in[8];
  const float* att  = (const float*)d_in[9];
  const float* bgat = (const float*)d_in[10];
  const float* W1   = (const float*)d_in[11];
  const float* b1   = (const float*)d_in[12];
  const float* W2   = (const float*)d_in[13];
  const float* b2   = (const float*)d_in[14];

  const int N = in_sizes[0] / 128;
  const int E = in_sizes[2];
  const int nb = (N + 255) / 256;

  float* hout   = (float*)d_out;               // [N,128]
  float* logits = hout + (size_t)N*128;        // [N,40]

  // workspace layout
  unsigned short* xlr = (unsigned short*)d_ws; // N*256 bf16 (xl | xr per row)
  int2*  erec   = (int2*)(xlr + (size_t)N*256);// E records (src, w)
  int*   rk     = (int*)(erec + E);            // E ranks
  int*   rowptr = rk + E;                      // N+1
  int*   cursor = rowptr + N + 1;              // N (deg)
  float* msum   = (float*)(cursor + N);        // 1
  int*   bsum   = (int*)(msum + 1);            // nb
  int*   boff   = bsum + nb;                   // nb
  float* bcat   = (float*)(boff + nb);         // 256
  unsigned short* wsp = (unsigned short*)(((uintptr_t)(bcat + 256) + 15) & ~(uintptr_t)15);
  unsigned short* Phi  = wsp;                  // 128*128
  unsigned short* Plo  = Phi + 16384;
  unsigned short* Lhi  = Plo + 16384;          // 256*128
  unsigned short* Llo  = Lhi + 32768;
  unsigned short* W1hi = Llo + 32768;          // 128*128
  unsigned short* W1lo = W1hi + 16384;
  unsigned short* W2hi = W1lo + 16384;         // 40*128
  unsigned short* W2lo = W2hi + 5120;

  hipMemsetAsync(cursor, 0, (size_t)(N + 1) * sizeof(int), stream);

  wprep<<<278, 256, 0, stream>>>(Wpre, Wl, Wr, W1, W2, bl, br,
                                 Phi, Plo, Lhi, Llo, W1hi, W1lo, W2hi, W2lo, bcat);
  count_mean<<<1024, 256, 0, stream>>>(ei, ew, cursor, rk, msum, E);
  scan1_kernel<<<nb, 256, 0, stream>>>(cursor, rowptr, bsum, N);
  scan2_kernel<<<1, 512, 0, stream>>>(bsum, boff, nb);
  scan3_kernel<<<nb, 256, 0, stream>>>(rowptr, boff, N);
  fill_kernel<<<(E + 255)/256, 256, 0, stream>>>(ei, ew, rowptr, rk, erec, E);

  const int gg = (N + 63) / 64;
  pre_kernel<<<gg, 512, 0, stream>>>(x, Phi, Plo, Lhi, Llo, bcat, hout, xlr, N);

  gather_kernel<<<(N + 15)/16, 256, 0, stream>>>(rowptr, erec, xlr, We, att, msum, bgat, hout, N);

  mlp_kernel<<<gg, 256, 0, stream>>>(hout, W1hi, W1lo, b1, W2hi, W2lo, b2, logits, N);
}